// Round 9
// baseline (1159.653 us; speedup 1.0000x reference)
//
#include <hip/hip_runtime.h>
#include <hip/hip_bf16.h>

#define DIM 384
#define HEADS 6
#define HD 64
#define LPIX 3136
#define HS 56
#define NPATCH 784
#define NF 392
#define SEQ 1569          // 1 + 392*4
#define BROWS 1568
#define HEXP 24
#define PR 96
#define HID 1536
#define SCALE 0.125f
#define EPSV 1e-5f
#define KPAD 1576         // SEQ padded to multiple of 8
#define QSTR 9456         // 6*KPAD, per-q row stride of S/A2 (bf16)

typedef short short8v __attribute__((ext_vector_type(8)));
typedef float f32x4 __attribute__((ext_vector_type(4)));
typedef unsigned short ushort;

__device__ __forceinline__ ushort f2b(float f) {
    __hip_bfloat16 h = __float2bfloat16(f);
    return reinterpret_cast<ushort&>(h);
}
__device__ __forceinline__ float b2f(ushort u) {
    unsigned int ui = ((unsigned int)u) << 16;
    return __uint_as_float(ui);
}
__device__ __forceinline__ float b2f_lo(unsigned int u) { return __uint_as_float(u << 16); }
__device__ __forceinline__ float b2f_hi(unsigned int u) { return __uint_as_float(u & 0xffff0000u); }

// ---------------- weight fp32 -> bf16 conversion (5 segments in one kernel) ----------------
struct CvtSeg { const float* s; ushort* d; int n; };
__global__ __launch_bounds__(256) void cvt_kernel(CvtSeg a, CvtSeg b, CvtSeg c, CvtSeg d, CvtSeg e) {
    CvtSeg seg;
    switch (blockIdx.y) { case 0: seg = a; break; case 1: seg = b; break; case 2: seg = c; break;
                          case 3: seg = d; break; default: seg = e; break; }
    int idx = (blockIdx.x * 256 + threadIdx.x) * 8;
    if (idx >= seg.n) return;
    float4 f0 = *reinterpret_cast<const float4*>(seg.s + idx);
    float4 f1 = *reinterpret_cast<const float4*>(seg.s + idx + 4);
    ushort u[8] = { f2b(f0.x), f2b(f0.y), f2b(f0.z), f2b(f0.w),
                    f2b(f1.x), f2b(f1.y), f2b(f1.z), f2b(f1.w) };
    *reinterpret_cast<uint4*>(seg.d + idx) = *reinterpret_cast<uint4*>(u);
}

// ---------------- conv (depthwise 3x3 + bias + residual) + fused patch-sum (means) ----------------
__global__ __launch_bounds__(384) void conv_kernel(const float* __restrict__ x,
                                                   const float* __restrict__ cw,
                                                   const float* __restrict__ cb,
                                                   float* __restrict__ x1,
                                                   float* __restrict__ means) {
    int l = blockIdx.x, c = threadIdx.x;
    int wid = c >> 6, lane = c & 63;
    int hh = l / HS, ww = l % HS;
    float acc = x[(long)l * DIM + c] + cb[c];
    #pragma unroll
    for (int kh = 0; kh < 3; kh++) {
        int h2 = hh + kh - 1;
        if (h2 < 0 || h2 >= HS) continue;
        #pragma unroll
        for (int kw = 0; kw < 3; kw++) {
            int w2 = ww + kw - 1;
            if (w2 < 0 || w2 >= HS) continue;
            acc += x[((long)h2 * HS + w2) * DIM + c] * cw[c * 9 + kh * 3 + kw];
        }
    }
    int p = (hh >> 1) * 28 + (ww >> 1);
    int t = ((hh & 1) << 1) | (ww & 1);
    x1[(long)(p * 4 + t) * DIM + c] = acc;
    float s = acc;
    #pragma unroll
    for (int off = 32; off >= 1; off >>= 1) s += __shfl_xor(s, off);
    __shared__ float wred[6];
    if (lane == 0) wred[wid] = s;
    __syncthreads();
    if (c == 0) atomicAdd(&means[p], wred[0] + wred[1] + wred[2] + wred[3] + wred[4] + wred[5]);
}

// ---------------- partition: rank flags + compaction in one block ----------------
__global__ __launch_bounds__(1024) void partition_kernel(const float* __restrict__ means, int* __restrict__ isfg,
                                                         int* __restrict__ pos, int* __restrict__ fgmap,
                                                         int* __restrict__ bgmap) {
    __shared__ float m_s[NPATCH];
    __shared__ unsigned char flag_s[NPATCH];
    __shared__ int scan_s[256];
    int tid = threadIdx.x;
    if (tid < NPATCH) m_s[tid] = means[tid];
    __syncthreads();
    if (tid < NPATCH) {
        float m = m_s[tid];
        int rank = 0;
        for (int q2 = 0; q2 < NPATCH; q2++) {
            float mq = m_s[q2];
            rank += (mq > m) || (mq == m && q2 < tid);
        }
        flag_s[tid] = (rank < NF) ? 1 : 0;
    }
    __syncthreads();
    if (tid < 256) {
        int base = tid * 4, cnt = 0;
        #pragma unroll
        for (int i = 0; i < 4; i++) { int p = base + i; if (p < NPATCH) cnt += flag_s[p]; }
        scan_s[tid] = cnt;
    }
    __syncthreads();
    for (int off = 1; off < 256; off <<= 1) {
        int add = 0;
        if (tid < 256 && tid >= off) add = scan_s[tid - off];
        __syncthreads();
        if (tid < 256) scan_s[tid] += add;
        __syncthreads();
    }
    if (tid < 256) {
        int base = tid * 4, cnt = 0;
        #pragma unroll
        for (int i = 0; i < 4; i++) { int p = base + i; if (p < NPATCH) cnt += flag_s[p]; }
        int run = scan_s[tid] - cnt;
        for (int i = 0; i < 4; i++) {
            int p = base + i;
            if (p >= NPATCH) break;
            int f = flag_s[p];
            if (f) { isfg[p] = 1; pos[p] = run; fgmap[run] = p; run++; }
            else   { isfg[p] = 0; pos[p] = p - run; bgmap[p - run] = p; }
        }
    }
}

// ---------------- gather foreground (with qa row 0) and background ----------------
__global__ __launch_bounds__(384) void gather_kernel(const float* __restrict__ x1, const float* __restrict__ qa,
                                                     const int* __restrict__ fgmap, const int* __restrict__ bgmap,
                                                     ushort* __restrict__ Xmsa_bf, ushort* __restrict__ B_bf) {
    int c = threadIdx.x;
    int bid = blockIdx.x;
    if (bid == 0) { Xmsa_bf[c] = f2b(qa[c]); return; }
    if (bid <= BROWS) {
        int r = bid - 1;
        int src = fgmap[r >> 2] * 4 + (r & 3);
        Xmsa_bf[(long)bid * DIM + c] = f2b(x1[(long)src * DIM + c]);
    } else {
        int r = bid - SEQ;
        int src = bgmap[r >> 2] * 4 + (r & 3);
        B_bf[(long)r * DIM + c] = f2b(x1[(long)src * DIM + c]);
    }
}

// ---------------- bf16 MFMA GEMM (BK=64: 2 k-substeps per barrier pair) ----------------
// C = alpha * A @ op(B) + bias (+silu) (+resid). A is bf16.
// OPB=1: B is [N][K] bf16 (A@B^T). OPB=0: B is [K][N] bf16 (requires BN=64, BK=64).
template<int BM, int BN, int BK, int OPB, int ACT, int OUTBF>
__global__ __launch_bounds__(256) void mgemm(
    const ushort* __restrict__ A, int lda, long long sA,
    const ushort* __restrict__ B, int ldb, long long sB,
    const float* __restrict__ bias, const float* __restrict__ resid, int ldr,
    void* __restrict__ Cv, int ldc, long long sC,
    int M, int N, int K, float alpha) {
    constexpr int LDT = BK + 8;
    constexpr int WR = (BM == 128 && BN == 128) ? 2 : ((BM == 128) ? 4 : 2);
    constexpr int WC = 4 / WR;
    constexpr int MFR = BM / WR / 16;
    constexpr int NFR = BN / WC / 16;
    constexpr int KH = BK / 32;
    __shared__ ushort As[BM * LDT];
    __shared__ ushort Bs[BN * LDT];
    int tid = threadIdx.x;
    int wid = tid >> 6, lane = tid & 63;
    int m0 = blockIdx.y * BM, n0 = blockIdx.x * BN;
    int bz = blockIdx.z;
    A += (long long)bz * sA;
    B += (long long)bz * sB;
    int wm = (wid / WC) * (BM / WR);
    int wn = (wid % WC) * (BN / WC);
    f32x4 acc[MFR][NFR];
    #pragma unroll
    for (int mi = 0; mi < MFR; mi++)
        #pragma unroll
        for (int ni = 0; ni < NFR; ni++) acc[mi][ni] = (f32x4){0.f, 0.f, 0.f, 0.f};

    for (int k0 = 0; k0 < K; k0 += BK) {
        { // ---- stage A: BM x BK ----
            constexpr int CPR = BK / 8;
            constexpr int CHA = BM * CPR / 256;
            #pragma unroll
            for (int t = 0; t < CHA; t++) {
                int chunk = tid + t * 256;
                int row = chunk / CPR, part = chunk % CPR;
                int gm = m0 + row, gk = k0 + part * 8;
                ushort* dst = &As[row * LDT + part * 8];
                if (gm < M && gk + 8 <= K) {
                    *reinterpret_cast<uint4*>(dst) =
                        *reinterpret_cast<const uint4*>(&A[(long long)gm * lda + gk]);
                } else {
                    #pragma unroll
                    for (int i = 0; i < 8; i++) {
                        int k = gk + i;
                        dst[i] = (gm < M && k < K) ? A[(long long)gm * lda + k] : (ushort)0;
                    }
                }
            }
        }
        if (OPB == 1) { // ---- stage B: BN x BK from [N][K] ----
            constexpr int CPR = BK / 8;
            constexpr int CHB = BN * CPR / 256;
            #pragma unroll
            for (int t = 0; t < CHB; t++) {
                int chunk = tid + t * 256;
                int row = chunk / CPR, part = chunk % CPR;
                int gn = n0 + row, gk = k0 + part * 8;
                ushort* dst = &Bs[row * LDT + part * 8];
                if (gn < N && gk + 8 <= K) {
                    *reinterpret_cast<uint4*>(dst) =
                        *reinterpret_cast<const uint4*>(&B[(long long)gn * ldb + gk]);
                } else {
                    #pragma unroll
                    for (int i = 0; i < 8; i++) {
                        int k = gk + i;
                        dst[i] = (gn < N && k < K) ? B[(long long)gn * ldb + k] : (ushort)0;
                    }
                }
            }
        } else { // ---- stage B: BK x BN from [K][N], transpose (BK=64, BN=64) ----
            int kr = tid >> 2, nn = (tid & 3) * 16;
            int gk = k0 + kr;
            ushort vals[16];
            if (gk < K && n0 + nn + 16 <= N) {
                *reinterpret_cast<uint4*>(vals) =
                    *reinterpret_cast<const uint4*>(&B[(long long)gk * ldb + n0 + nn]);
                *reinterpret_cast<uint4*>(vals + 8) =
                    *reinterpret_cast<const uint4*>(&B[(long long)gk * ldb + n0 + nn + 8]);
            } else {
                #pragma unroll
                for (int i = 0; i < 16; i++) {
                    int gn = n0 + nn + i;
                    vals[i] = (gk < K && gn < N) ? B[(long long)gk * ldb + gn] : (ushort)0;
                }
            }
            #pragma unroll
            for (int i = 0; i < 16; i++) Bs[(nn + i) * LDT + kr] = vals[i];
        }
        __syncthreads();
        #pragma unroll
        for (int kh = 0; kh < KH; kh++) {
            short8v a[MFR], b[NFR];
            int kcol = kh * 32 + (lane >> 4) * 8;
            #pragma unroll
            for (int mi = 0; mi < MFR; mi++)
                a[mi] = *reinterpret_cast<const short8v*>(&As[(wm + mi * 16 + (lane & 15)) * LDT + kcol]);
            #pragma unroll
            for (int ni = 0; ni < NFR; ni++)
                b[ni] = *reinterpret_cast<const short8v*>(&Bs[(wn + ni * 16 + (lane & 15)) * LDT + kcol]);
            #pragma unroll
            for (int mi = 0; mi < MFR; mi++)
                #pragma unroll
                for (int ni = 0; ni < NFR; ni++)
                    acc[mi][ni] = __builtin_amdgcn_mfma_f32_16x16x32_bf16(a[mi], b[ni], acc[mi][ni], 0, 0, 0);
        }
        __syncthreads();
    }
    ushort* C16 = (ushort*)Cv;
    float* C32 = (float*)Cv;
    #pragma unroll
    for (int mi = 0; mi < MFR; mi++) {
        #pragma unroll
        for (int j = 0; j < 4; j++) {
            int gm = m0 + wm + mi * 16 + (lane >> 4) * 4 + j;
            if (gm >= M) continue;
            #pragma unroll
            for (int ni = 0; ni < NFR; ni++) {
                int gn = n0 + wn + ni * 16 + (lane & 15);
                if (gn >= N) continue;
                float v = acc[mi][ni][j] * alpha;
                if (bias) v += bias[gn];
                if (ACT == 1) v = v / (1.f + __expf(-v));
                if (resid) v += resid[(long long)gm * ldr + gn];
                long long ci = bz * sC + (long long)gm * ldc + gn;
                if (OUTBF) C16[ci] = f2b(v); else C32[ci] = v;
            }
        }
    }
}

// ---------------- modulated attention v5: e-ownership per wave ----------------
// wave w owns channels {3w,3w+1,3w+2} for ALL k -> reductions intra-wave only.
// S staged transposed into 3 packed-uint LDS arrays (stride-1 b32 reads);
// a2 accumulated cross-wave via LDS atomicAdd into per-head stride-1 arrays.
__global__ __launch_bounds__(512, 2) void modattn_kernel(
    ushort* __restrict__ S,
    const float* __restrict__ ap1_w, const float* __restrict__ ap1_b,
    const float* __restrict__ ap2_w, const float* __restrict__ ap2_b) {
    int q = blockIdx.x, tid = threadIdx.x;
    int wv = tid >> 6, lane = tid & 63;
    __shared__ unsigned int sk32[3 * KPAD];   // packed bf16 pairs [h/2][k]; reused as out [h][KPAD] ushort
    __shared__ float a2buf[6 * KPAD];         // [h][KPAD] accumulators
    __shared__ float w1s[144], w2s[144], b1s[24], b2s[6];
    if (tid < 144) { w1s[tid] = ap1_w[tid]; w2s[tid] = ap2_w[tid]; }
    if (tid < 24) b1s[tid] = ap1_b[tid];
    if (tid < 6)  b2s[tid] = ap2_b[tid];
    { // zero a2buf: 9456 floats = 2364 uint4
        uint4* z = reinterpret_cast<uint4*>(a2buf);
        uint4 zero = {0, 0, 0, 0};
        #pragma unroll
        for (int t = 0; t < 5; t++) { int i = tid + t * 512; if (i < 2364) z[i] = zero; }
    }
    { // stage S [h][KPAD] -> transposed packed sk32[h>>1][k] (ushort lane h&1)
        const uint4* g = reinterpret_cast<const uint4*>(S + (long long)q * QSTR);
        ushort* sku = reinterpret_cast<ushort*>(sk32);
        #pragma unroll
        for (int t = 0; t < 3; t++) {
            int i = tid + t * 512;
            if (i < 1182) {
                uint4 v = g[i];
                int h = i / 197;               // KPAD/8 = 197 uint4 per head row
                int k0 = (i - h * 197) * 8;
                int base = (h >> 1) * 2 * KPAD + (h & 1);
                ushort u[8];
                *reinterpret_cast<uint4*>(u) = v;
                #pragma unroll
                for (int x2 = 0; x2 < 8; x2++) sku[base + 2 * (k0 + x2)] = u[x2];
            }
        }
    }
    __syncthreads();
    // ---- phase 1: a1 = W1 s + b1 for this wave's 3 channels; max; exp; sum ----
    int e0 = wv * 3;
    int kl = (lane + wv * 8) & 63;           // per-wave rotated lane->k map (de-conflicts atomics)
    float w1a[3][6], b1a[3];
    #pragma unroll
    for (int e = 0; e < 3; e++) {
        b1a[e] = b1s[e0 + e];
        #pragma unroll
        for (int h = 0; h < 6; h++) w1a[e][h] = w1s[(e0 + e) * 6 + h];
    }
    float p[25][3];
    float mx0 = -3.4e38f, mx1 = -3.4e38f, mx2 = -3.4e38f;
    #pragma unroll
    for (int j = 0; j < 25; j++) {
        int k = kl + j * 64;
        bool val = k < SEQ;
        int kc = val ? k : 0;
        unsigned int u01 = sk32[kc], u23 = sk32[KPAD + kc], u45 = sk32[2 * KPAD + kc];
        float sv[6] = { b2f_lo(u01), b2f_hi(u01), b2f_lo(u23), b2f_hi(u23), b2f_lo(u45), b2f_hi(u45) };
        #pragma unroll
        for (int e = 0; e < 3; e++) {
            float a = b1a[e];
            #pragma unroll
            for (int h = 0; h < 6; h++) a = fmaf(sv[h], w1a[e][h], a);
            p[j][e] = a;
        }
        if (val) { mx0 = fmaxf(mx0, p[j][0]); mx1 = fmaxf(mx1, p[j][1]); mx2 = fmaxf(mx2, p[j][2]); }
    }
    #pragma unroll
    for (int off = 32; off >= 1; off >>= 1) {
        mx0 = fmaxf(mx0, __shfl_xor(mx0, off));
        mx1 = fmaxf(mx1, __shfl_xor(mx1, off));
        mx2 = fmaxf(mx2, __shfl_xor(mx2, off));
    }
    float s0 = 0.f, s1 = 0.f, s2 = 0.f;
    #pragma unroll
    for (int j = 0; j < 25; j++) {
        int k = kl + j * 64;
        bool val = k < SEQ;
        float p0 = val ? __expf(p[j][0] - mx0) : 0.f;
        float p1 = val ? __expf(p[j][1] - mx1) : 0.f;
        float p2 = val ? __expf(p[j][2] - mx2) : 0.f;
        p[j][0] = p0; p[j][1] = p1; p[j][2] = p2;
        s0 += p0; s1 += p1; s2 += p2;
    }
    #pragma unroll
    for (int off = 32; off >= 1; off >>= 1) {
        s0 += __shfl_xor(s0, off);
        s1 += __shfl_xor(s1, off);
        s2 += __shfl_xor(s2, off);
    }
    float i0 = 1.f / s0, i1 = 1.f / s1, i2 = 1.f / s2;
    // ---- phase 2: a2 partial = p * W2^T, atomically accumulated per (k,h) ----
    float w2a[6][3];
    #pragma unroll
    for (int h = 0; h < 6; h++)
        #pragma unroll
        for (int e = 0; e < 3; e++) w2a[h][e] = w2s[h * 24 + e0 + e];
    #pragma unroll
    for (int j = 0; j < 25; j++) {
        int k = kl + j * 64;
        if (k >= SEQ) continue;
        float p0 = p[j][0] * i0, p1 = p[j][1] * i1, p2 = p[j][2] * i2;
        #pragma unroll
        for (int h = 0; h < 6; h++) {
            float v = p0 * w2a[h][0] + p1 * w2a[h][1] + p2 * w2a[h][2];
            atomicAdd(&a2buf[h * KPAD + k], v);
        }
    }
    __syncthreads();
    // ---- phase 3: write out bf16 [h][KPAD] into sk32 region, then vectorized global store ----
    ushort* osk = reinterpret_cast<ushort*>(sk32);
    #pragma unroll
    for (int j = 0; j < 4; j++) {
        int k = tid + j * 512;
        if (k >= KPAD) break;
        bool val = k < SEQ;
        #pragma unroll
        for (int h = 0; h < 6; h++) {
            float v = val ? (a2buf[h * KPAD + k] + b2s[h]) : 0.f;
            osk[h * KPAD + k] = f2b(v);
        }
    }
    __syncthreads();
    {
        const uint4* l = reinterpret_cast<const uint4*>(osk);
        uint4* g = reinterpret_cast<uint4*>(S + (long long)q * QSTR);
        #pragma unroll
        for (int t = 0; t < 3; t++) {
            int i = tid + t * 512;
            if (i < 1182) g[i] = l[i];
        }
    }
}

// ---------------- single-query attention pooling (per head), vectorized ----------------
__global__ __launch_bounds__(512) void sqa_attn_kernel(const float* __restrict__ kv, const float* __restrict__ qa2,
                                                       float* __restrict__ x1h) {
    int h = blockIdx.x, tid = threadIdx.x;
    int wid = tid >> 6, lane = tid & 63;
    __shared__ float q_s[HD];
    __shared__ float l_s[BROWS];
    __shared__ float red8[8];
    __shared__ float pvred[8][HD];
    __shared__ float gmv;
    if (tid < HD) q_s[tid] = qa2[h * HD + tid];
    __syncthreads();
    float lmax = -1e30f;
    #pragma unroll
    for (int j = 0; j < 4; j++) {
        int s = tid + j * 512;
        if (s < BROWS) {
            const float4* kr = reinterpret_cast<const float4*>(kv + (long long)s * 768 + h * HD);
            float d = 0.f;
            #pragma unroll
            for (int i = 0; i < 16; i++) {
                float4 f = kr[i];
                d = fmaf(f.x, q_s[i * 4 + 0], d); d = fmaf(f.y, q_s[i * 4 + 1], d);
                d = fmaf(f.z, q_s[i * 4 + 2], d); d = fmaf(f.w, q_s[i * 4 + 3], d);
            }
            d *= SCALE;
            l_s[s] = d;
            lmax = fmaxf(lmax, d);
        }
    }
    #pragma unroll
    for (int off = 32; off >= 1; off >>= 1) lmax = fmaxf(lmax, __shfl_xor(lmax, off));
    if (lane == 0) red8[wid] = lmax;
    __syncthreads();
    if (tid == 0) {
        float v = red8[0];
        #pragma unroll
        for (int w = 1; w < 8; w++) v = fmaxf(v, red8[w]);
        gmv = v;
    }
    __syncthreads();
    float gmax = gmv;
    float lsum = 0.f;
    #pragma unroll
    for (int j = 0; j < 4; j++) {
        int s = tid + j * 512;
        if (s < BROWS) { float pp = __expf(l_s[s] - gmax); l_s[s] = pp; lsum += pp; }
    }
    #pragma unroll
    for (int off = 32; off >= 1; off >>= 1) lsum += __shfl_xor(lsum, off);
    if (lane == 0) red8[wid] = lsum;
    __syncthreads();
    if (tid == 0) {
        float v = 0.f;
        #pragma unroll
        for (int w = 0; w < 8; w++) v += red8[w];
        gmv = 1.f / v;
    }
    __syncthreads();
    float inv = gmv;
    int d = tid & 63, g = tid >> 6;
    float acc = 0.f;
    for (int s = g; s < BROWS; s += 8)
        acc = fmaf(l_s[s], kv[(long long)s * 768 + 384 + h * HD + d], acc);
    pvred[g][d] = acc;
    __syncthreads();
    if (tid < HD) {
        float v = 0.f;
        #pragma unroll
        for (int w = 0; w < 8; w++) v += pvred[w][tid];
        x1h[h * HD + tid] = v * inv;
    }
}

// ---------------- sqa mlp: sp1 -> LN -> relu -> sp2 (+ fused qa2 copy to out) ----------------
__global__ __launch_bounds__(384) void sqa_mlp_kernel(const float* __restrict__ x1h,
                                                      const float* __restrict__ sp1_w, const float* __restrict__ sp1_b,
                                                      const float* __restrict__ pn_w, const float* __restrict__ pn_b,
                                                      const float* __restrict__ sp2_w, const float* __restrict__ sp2_b,
                                                      float* __restrict__ z,
                                                      const float* __restrict__ mp, float* __restrict__ dq) {
    __shared__ float y_s[PR];
    __shared__ float x_s[DIM];
    __shared__ float mv[2];
    int tid = threadIdx.x;
    dq[tid] = mp[tid];
    x_s[tid] = x1h[tid];
    __syncthreads();
    if (tid < PR) {
        float a = sp1_b[tid];
        for (int c = 0; c < DIM; c++) a += sp1_w[tid * DIM + c] * x_s[c];
        y_s[tid] = a;
    }
    __syncthreads();
    if (tid == 0) {
        float m = 0.f; for (int i = 0; i < PR; i++) m += y_s[i]; m /= (float)PR;
        float v = 0.f; for (int i = 0; i < PR; i++) { float d = y_s[i] - m; v += d * d; } v /= (float)PR;
        mv[0] = m; mv[1] = rsqrtf(v + EPSV);
    }
    __syncthreads();
    if (tid < PR) {
        float yn = (y_s[tid] - mv[0]) * mv[1] * pn_w[tid] + pn_b[tid];
        y_s[tid] = fmaxf(yn, 0.f);
    }
    __syncthreads();
    float a = sp2_b[tid];
    for (int j = 0; j < PR; j++) a += sp2_w[tid * PR + j] * y_s[j];
    z[tid] = a;
}

// ---------------- scatter + unpatchify + LN1 + residual + LN2 (shuffle reductions) ----------------
__global__ __launch_bounds__(384) void scatter_ln_kernel(
    const float* __restrict__ x, const float* __restrict__ mpout, const ushort* __restrict__ B_bf,
    const float* __restrict__ z, const int* __restrict__ isfg, const int* __restrict__ pos,
    const float* __restrict__ n1w, const float* __restrict__ n1b,
    const float* __restrict__ n2w, const float* __restrict__ n2b,
    float* __restrict__ x_mid, ushort* __restrict__ hnorm_bf) {
    int l = blockIdx.x, c = threadIdx.x;
    int wid = c >> 6, lane = c & 63;
    int hh = l / HS, ww = l % HS;
    int p = (hh >> 1) * 28 + (ww >> 1);
    int t = ((hh & 1) << 1) | (ww & 1);
    float v;
    if (isfg[p]) v = mpout[(long long)(1 + pos[p] * 4 + t) * DIM + c];
    else v = b2f(B_bf[(long long)(pos[p] * 4 + t) * DIM + c]) + z[c];
    __shared__ float r0[8], r1[8], r2[8], r3[8];
    float s1 = v, s2 = v * v;
    #pragma unroll
    for (int off = 32; off >= 1; off >>= 1) { s1 += __shfl_xor(s1, off); s2 += __shfl_xor(s2, off); }
    if (lane == 0) { r0[wid] = s1; r1[wid] = s2; }
    __syncthreads();
    float mean = (r0[0] + r0[1] + r0[2] + r0[3] + r0[4] + r0[5]) / (float)DIM;
    float var = (r1[0] + r1[1] + r1[2] + r1[3] + r1[4] + r1[5]) / (float)DIM - mean * mean;
    float xm = x[(long long)l * DIM + c] + (v - mean) * rsqrtf(var + EPSV) * n1w[c] + n1b[c];
    x_mid[(long long)l * DIM + c] = xm;
    s1 = xm; s2 = xm * xm;
    #pragma unroll
    for (int off = 32; off >= 1; off >>= 1) { s1 += __shfl_xor(s1, off); s2 += __shfl_xor(s2, off); }
    if (lane == 0) { r2[wid] = s1; r3[wid] = s2; }
    __syncthreads();
    float m2 = (r2[0] + r2[1] + r2[2] + r2[3] + r2[4] + r2[5]) / (float)DIM;
    float v2 = (r3[0] + r3[1] + r3[2] + r3[3] + r3[4] + r3[5]) / (float)DIM - m2 * m2;
    hnorm_bf[(long long)l * DIM + c] = f2b((xm - m2) * rsqrtf(v2 + EPSV) * n2w[c] + n2b[c]);
}

extern "C" void kernel_launch(void* const* d_in, const int* in_sizes, int n_in,
                              void* d_out, int out_size, void* d_ws, size_t ws_size,
                              hipStream_t stream) {
    const float* x       = (const float*)d_in[0];
    const float* qa      = (const float*)d_in[1];
    const float* conv_w  = (const float*)d_in[2];
    const float* conv_b  = (const float*)d_in[3];
    const float* n1w     = (const float*)d_in[4];
    const float* n1b     = (const float*)d_in[5];
    const float* n2w     = (const float*)d_in[6];
    const float* n2b     = (const float*)d_in[7];
    const float* qkv_w   = (const float*)d_in[8];
    const float* qkv_b   = (const float*)d_in[9];
    const float* mproj_w = (const float*)d_in[10];
    const float* mproj_b = (const float*)d_in[11];
    const float* ap1_w   = (const float*)d_in[12];
    const float* ap1_b   = (const float*)d_in[13];
    const float* ap2_w   = (const float*)d_in[14];
    const float* ap2_b   = (const float*)d_in[15];
    const float* kv_w    = (const float*)d_in[16];
    const float* kv_b    = (const float*)d_in[17];
    const float* sp1_w   = (const float*)d_in[18];
    const float* sp1_b   = (const float*)d_in[19];
    const float* sp2_w   = (const float*)d_in[20];
    const float* sp2_b   = (const float*)d_in[21];
    const float* pn_w    = (const float*)d_in[22];
    const float* pn_b    = (const float*)d_in[23];
    const float* fc1_w   = (const float*)d_in[24];
    const float* fc1_b   = (const float*)d_in[25];
    const float* fc2_w   = (const float*)d_in[26];
    const float* fc2_b   = (const float*)d_in[27];
    float* out = (float*)d_out;
    float* ws  = (float*)d_ws;

    // ---- workspace layout (float offsets) ----
    const long long X1_OFF    = 0;           // x1 fp32; later qkvb_bf
    const long long BMAT_OFF  = 1204224;     // Bmat_bf (301,056 f as 602,112 u16) — read by kv GEMM AND scatter
    const long long S_OFF     = 1806336;     // S16/A2 bf16 in place; later kv_out/hnorm/hact
    const long long MPOUT_OFF = 16576912;    // Xmsa_bf first, then mpout fp32
    const long long XMID_OFF  = 17179408;    // attn_bf first (dead after mproj), then xmid fp32
    const long long WBF_OFF   = 18383632;
    const long long MEANS_OFF = 19415824;
    const long long X1H_OFF   = 19416608;
    const long long Z_OFF     = 19416992;
    const long long ISFG_OFF  = 19418160;
    const long long POS_OFF   = 19418944;
    const long long FGMAP_OFF = 19419728;
    const long long BGMAP_OFF = 19420120;

    float*  x1_arr  = ws + X1_OFF;
    float*  mpout   = ws + MPOUT_OFF;
    float*  xmid    = ws + XMID_OFF;
    float*  means   = ws + MEANS_OFF;
    float*  x1h     = ws + X1H_OFF;
    float*  zvec    = ws + Z_OFF;
    int*    isfg    = (int*)(ws + ISFG_OFF);
    int*    pos     = (int*)(ws + POS_OFF);
    int*    fgmap   = (int*)(ws + FGMAP_OFF);
    int*    bgmap   = (int*)(ws + BGMAP_OFF);

    ushort* S16     = (ushort*)(ws + S_OFF);
    ushort* qkvb_bf = (ushort*)(ws + X1_OFF);
    ushort* Xmsa_bf = (ushort*)(ws + MPOUT_OFF);
    ushort* Bmat_bf = (ushort*)(ws + BMAT_OFF);          // own slot — NOT aliased with xmid
    ushort* attn_bf = (ushort*)(ws + XMID_OFF);          // dead before scatter writes xmid
    float*  kv_out  = ws + S_OFF;
    ushort* hnorm_bf= (ushort*)(ws + S_OFF + 1204224);
    ushort* hact_bf = (ushort*)(ws + S_OFF + 1806336);

    ushort* wbf      = (ushort*)(ws + WBF_OFF);
    ushort* qkvw_bf  = wbf;
    ushort* mprojw_bf= wbf + 442368;
    ushort* kvw_bf   = wbf + 589824;
    ushort* fc1w_bf  = wbf + 884736;
    ushort* fc2w_bf  = wbf + 1474560;

    { // weight conversion
        CvtSeg s0{qkv_w, qkvw_bf, 442368};
        CvtSeg s1{mproj_w, mprojw_bf, 147456};
        CvtSeg s2{kv_w, kvw_bf, 294912};
        CvtSeg s3{fc1_w, fc1w_bf, 589824};
        CvtSeg s4{fc2_w, fc2w_bf, 589824};
        dim3 g(288, 5, 1);
        cvt_kernel<<<g, 256, 0, stream>>>(s0, s1, s2, s3, s4);
    }

    hipMemsetAsync(means, 0, NPATCH * sizeof(float), stream);
    conv_kernel<<<LPIX, 384, 0, stream>>>(x, conv_w, conv_b, x1_arr, means);
    partition_kernel<<<1, 1024, 0, stream>>>(means, isfg, pos, fgmap, bgmap);
    gather_kernel<<<SEQ + BROWS, 384, 0, stream>>>(x1_arr, qa, fgmap, bgmap, Xmsa_bf, Bmat_bf);

    { // qkv: (1569x384) @ (1152x384)^T -> bf16
        dim3 g(18, 25, 1);
        mgemm<64,64,64,1,0,1><<<g, 256, 0, stream>>>(Xmsa_bf, DIM, 0, qkvw_bf, DIM, 0, qkv_b,
                                                     nullptr, 0, qkvb_bf, 1152, 0, SEQ, 1152, DIM, 1.f);
    }
    { // S[q][h][k] = SCALE * q@k^T -> bf16, batched heads (K=64: single K-step)
        dim3 g(13, 13, 6);
        mgemm<128,128,64,1,0,1><<<g, 256, 0, stream>>>(qkvb_bf, 1152, 64, qkvb_bf + 384, 1152, 64, nullptr,
                                                       nullptr, 0, S16, QSTR, (long long)KPAD, SEQ, SEQ, HD, SCALE);
    }
    modattn_kernel<<<SEQ, 512, 0, stream>>>(S16, ap1_w, ap1_b, ap2_w, ap2_b);
    { // PV: attn_bf[q][h*64+d] = A2[h] @ V[h]
        dim3 g(1, 25, 6);
        mgemm<64,64,64,0,0,1><<<g, 256, 0, stream>>>(S16, QSTR, (long long)KPAD, qkvb_bf + 768, 1152, 64, nullptr,
                                                     nullptr, 0, attn_bf, DIM, 64, SEQ, HD, SEQ, 1.f);
    }
    { // mproj -> fp32 mpout
        dim3 g(6, 25, 1);
        mgemm<64,64,64,1,0,0><<<g, 256, 0, stream>>>(attn_bf, DIM, 0, mprojw_bf, DIM, 0, mproj_b,
                                                     nullptr, 0, mpout, DIM, 0, SEQ, DIM, DIM, 1.f);
    }
    { // kv -> fp32
        dim3 g(12, 25, 1);
        mgemm<64,64,64,1,0,0><<<g, 256, 0, stream>>>(Bmat_bf, DIM, 0, kvw_bf, DIM, 0, kv_b,
                                                     nullptr, 0, kv_out, 768, 0, BROWS, 768, DIM, 1.f);
    }
    sqa_attn_kernel<<<HEADS, 512, 0, stream>>>(kv_out, mpout /* row 0 = qa2 */, x1h);
    sqa_mlp_kernel<<<1, 384, 0, stream>>>(x1h, sp1_w, sp1_b, pn_w, pn_b, sp2_w, sp2_b, zvec,
                                          mpout, out + (long long)LPIX * DIM);
    scatter_ln_kernel<<<LPIX, 384, 0, stream>>>(x, mpout, Bmat_bf, zvec, isfg, pos,
                                                n1w, n1b, n2w, n2b, xmid, hnorm_bf);
    { // fc1 + silu -> bf16
        dim3 g(12, 25, 1);
        mgemm<128,128,64,1,1,1><<<g, 256, 0, stream>>>(hnorm_bf, DIM, 0, fc1w_bf, DIM, 0, fc1_b,
                                                       nullptr, 0, hact_bf, HID, 0, LPIX, HID, DIM, 1.f);
    }
    { // fc2 + residual -> out fp32
        dim3 g(6, 50, 1);
        mgemm<64,64,64,1,0,0><<<g, 256, 0, stream>>>(hact_bf, HID, 0, fc2w_bf, HID, 0, fc2_b,
                                                     xmid, DIM, out, DIM, 0, LPIX, DIM, HID, 1.f);
    }
}

// Round 10
// 556.805 us; speedup vs baseline: 2.0827x; 2.0827x over previous
//
#include <hip/hip_runtime.h>
#include <hip/hip_bf16.h>

#define DIM 384
#define HEADS 6
#define HD 64
#define LPIX 3136
#define HS 56
#define NPATCH 784
#define NF 392
#define SEQ 1569          // 1 + 392*4
#define BROWS 1568
#define HEXP 24
#define PR 96
#define HID 1536
#define SCALE 0.125f
#define EPSV 1e-5f
#define KPAD 1576         // SEQ padded to multiple of 8
#define QSTR 9456         // 6*KPAD, per-q row stride of S/A2 (bf16)

typedef short short8v __attribute__((ext_vector_type(8)));
typedef float f32x4 __attribute__((ext_vector_type(4)));
typedef unsigned short ushort;

__device__ __forceinline__ ushort f2b(float f) {
    __hip_bfloat16 h = __float2bfloat16(f);
    return reinterpret_cast<ushort&>(h);
}
__device__ __forceinline__ float b2f(ushort u) {
    unsigned int ui = ((unsigned int)u) << 16;
    return __uint_as_float(ui);
}

// ---------------- weight fp32 -> bf16 conversion (5 segments in one kernel) ----------------
struct CvtSeg { const float* s; ushort* d; int n; };
__global__ __launch_bounds__(256) void cvt_kernel(CvtSeg a, CvtSeg b, CvtSeg c, CvtSeg d, CvtSeg e) {
    CvtSeg seg;
    switch (blockIdx.y) { case 0: seg = a; break; case 1: seg = b; break; case 2: seg = c; break;
                          case 3: seg = d; break; default: seg = e; break; }
    int idx = (blockIdx.x * 256 + threadIdx.x) * 8;
    if (idx >= seg.n) return;
    float4 f0 = *reinterpret_cast<const float4*>(seg.s + idx);
    float4 f1 = *reinterpret_cast<const float4*>(seg.s + idx + 4);
    ushort u[8] = { f2b(f0.x), f2b(f0.y), f2b(f0.z), f2b(f0.w),
                    f2b(f1.x), f2b(f1.y), f2b(f1.z), f2b(f1.w) };
    *reinterpret_cast<uint4*>(seg.d + idx) = *reinterpret_cast<uint4*>(u);
}

// ---------------- conv (depthwise 3x3 + bias + residual) + fused patch-sum (means) ----------------
__global__ __launch_bounds__(384) void conv_kernel(const float* __restrict__ x,
                                                   const float* __restrict__ cw,
                                                   const float* __restrict__ cb,
                                                   float* __restrict__ x1,
                                                   float* __restrict__ means) {
    int l = blockIdx.x, c = threadIdx.x;
    int wid = c >> 6, lane = c & 63;
    int hh = l / HS, ww = l % HS;
    float acc = x[(long)l * DIM + c] + cb[c];
    #pragma unroll
    for (int kh = 0; kh < 3; kh++) {
        int h2 = hh + kh - 1;
        if (h2 < 0 || h2 >= HS) continue;
        #pragma unroll
        for (int kw = 0; kw < 3; kw++) {
            int w2 = ww + kw - 1;
            if (w2 < 0 || w2 >= HS) continue;
            acc += x[((long)h2 * HS + w2) * DIM + c] * cw[c * 9 + kh * 3 + kw];
        }
    }
    int p = (hh >> 1) * 28 + (ww >> 1);
    int t = ((hh & 1) << 1) | (ww & 1);
    x1[(long)(p * 4 + t) * DIM + c] = acc;
    float s = acc;
    #pragma unroll
    for (int off = 32; off >= 1; off >>= 1) s += __shfl_xor(s, off);
    __shared__ float wred[6];
    if (lane == 0) wred[wid] = s;
    __syncthreads();
    if (c == 0) atomicAdd(&means[p], wred[0] + wred[1] + wred[2] + wred[3] + wred[4] + wred[5]);
}

// ---------------- partition: rank flags + compaction in one block ----------------
__global__ __launch_bounds__(1024) void partition_kernel(const float* __restrict__ means, int* __restrict__ isfg,
                                                         int* __restrict__ pos, int* __restrict__ fgmap,
                                                         int* __restrict__ bgmap) {
    __shared__ float m_s[NPATCH];
    __shared__ unsigned char flag_s[NPATCH];
    __shared__ int scan_s[256];
    int tid = threadIdx.x;
    if (tid < NPATCH) m_s[tid] = means[tid];
    __syncthreads();
    if (tid < NPATCH) {
        float m = m_s[tid];
        int rank = 0;
        for (int q2 = 0; q2 < NPATCH; q2++) {
            float mq = m_s[q2];
            rank += (mq > m) || (mq == m && q2 < tid);
        }
        flag_s[tid] = (rank < NF) ? 1 : 0;
    }
    __syncthreads();
    if (tid < 256) {
        int base = tid * 4, cnt = 0;
        #pragma unroll
        for (int i = 0; i < 4; i++) { int p = base + i; if (p < NPATCH) cnt += flag_s[p]; }
        scan_s[tid] = cnt;
    }
    __syncthreads();
    for (int off = 1; off < 256; off <<= 1) {
        int add = 0;
        if (tid < 256 && tid >= off) add = scan_s[tid - off];
        __syncthreads();
        if (tid < 256) scan_s[tid] += add;
        __syncthreads();
    }
    if (tid < 256) {
        int base = tid * 4, cnt = 0;
        #pragma unroll
        for (int i = 0; i < 4; i++) { int p = base + i; if (p < NPATCH) cnt += flag_s[p]; }
        int run = scan_s[tid] - cnt;
        for (int i = 0; i < 4; i++) {
            int p = base + i;
            if (p >= NPATCH) break;
            int f = flag_s[p];
            if (f) { isfg[p] = 1; pos[p] = run; fgmap[run] = p; run++; }
            else   { isfg[p] = 0; pos[p] = p - run; bgmap[p - run] = p; }
        }
    }
}

// ---------------- gather foreground (with qa row 0) and background ----------------
__global__ __launch_bounds__(384) void gather_kernel(const float* __restrict__ x1, const float* __restrict__ qa,
                                                     const int* __restrict__ fgmap, const int* __restrict__ bgmap,
                                                     ushort* __restrict__ Xmsa_bf, ushort* __restrict__ B_bf) {
    int c = threadIdx.x;
    int bid = blockIdx.x;
    if (bid == 0) { Xmsa_bf[c] = f2b(qa[c]); return; }
    if (bid <= BROWS) {
        int r = bid - 1;
        int src = fgmap[r >> 2] * 4 + (r & 3);
        Xmsa_bf[(long)bid * DIM + c] = f2b(x1[(long)src * DIM + c]);
    } else {
        int r = bid - SEQ;
        int src = bgmap[r >> 2] * 4 + (r & 3);
        B_bf[(long)r * DIM + c] = f2b(x1[(long)src * DIM + c]);
    }
}

// ---------------- bf16 MFMA GEMM (BK=64: 2 k-substeps per barrier pair) ----------------
// C = alpha * A @ op(B) + bias (+silu) (+resid). A is bf16.
// OPB=1: B is [N][K] bf16 (A@B^T). OPB=0: B is [K][N] bf16 (requires BN=64, BK=64).
template<int BM, int BN, int BK, int OPB, int ACT, int OUTBF>
__global__ __launch_bounds__(256) void mgemm(
    const ushort* __restrict__ A, int lda, long long sA,
    const ushort* __restrict__ B, int ldb, long long sB,
    const float* __restrict__ bias, const float* __restrict__ resid, int ldr,
    void* __restrict__ Cv, int ldc, long long sC,
    int M, int N, int K, float alpha) {
    constexpr int LDT = BK + 8;
    constexpr int WR = (BM == 128 && BN == 128) ? 2 : ((BM == 128) ? 4 : 2);
    constexpr int WC = 4 / WR;
    constexpr int MFR = BM / WR / 16;
    constexpr int NFR = BN / WC / 16;
    constexpr int KH = BK / 32;
    __shared__ ushort As[BM * LDT];
    __shared__ ushort Bs[BN * LDT];
    int tid = threadIdx.x;
    int wid = tid >> 6, lane = tid & 63;
    int m0 = blockIdx.y * BM, n0 = blockIdx.x * BN;
    int bz = blockIdx.z;
    A += (long long)bz * sA;
    B += (long long)bz * sB;
    int wm = (wid / WC) * (BM / WR);
    int wn = (wid % WC) * (BN / WC);
    f32x4 acc[MFR][NFR];
    #pragma unroll
    for (int mi = 0; mi < MFR; mi++)
        #pragma unroll
        for (int ni = 0; ni < NFR; ni++) acc[mi][ni] = (f32x4){0.f, 0.f, 0.f, 0.f};

    for (int k0 = 0; k0 < K; k0 += BK) {
        { // ---- stage A: BM x BK ----
            constexpr int CPR = BK / 8;
            constexpr int CHA = BM * CPR / 256;
            #pragma unroll
            for (int t = 0; t < CHA; t++) {
                int chunk = tid + t * 256;
                int row = chunk / CPR, part = chunk % CPR;
                int gm = m0 + row, gk = k0 + part * 8;
                ushort* dst = &As[row * LDT + part * 8];
                if (gm < M && gk + 8 <= K) {
                    *reinterpret_cast<uint4*>(dst) =
                        *reinterpret_cast<const uint4*>(&A[(long long)gm * lda + gk]);
                } else {
                    #pragma unroll
                    for (int i = 0; i < 8; i++) {
                        int k = gk + i;
                        dst[i] = (gm < M && k < K) ? A[(long long)gm * lda + k] : (ushort)0;
                    }
                }
            }
        }
        if (OPB == 1) { // ---- stage B: BN x BK from [N][K] ----
            constexpr int CPR = BK / 8;
            constexpr int CHB = BN * CPR / 256;
            #pragma unroll
            for (int t = 0; t < CHB; t++) {
                int chunk = tid + t * 256;
                int row = chunk / CPR, part = chunk % CPR;
                int gn = n0 + row, gk = k0 + part * 8;
                ushort* dst = &Bs[row * LDT + part * 8];
                if (gn < N && gk + 8 <= K) {
                    *reinterpret_cast<uint4*>(dst) =
                        *reinterpret_cast<const uint4*>(&B[(long long)gn * ldb + gk]);
                } else {
                    #pragma unroll
                    for (int i = 0; i < 8; i++) {
                        int k = gk + i;
                        dst[i] = (gn < N && k < K) ? B[(long long)gn * ldb + k] : (ushort)0;
                    }
                }
            }
        } else { // ---- stage B: BK x BN from [K][N], transpose (BK=64, BN=64) ----
            int kr = tid >> 2, nn = (tid & 3) * 16;
            int gk = k0 + kr;
            ushort vals[16];
            if (gk < K && n0 + nn + 16 <= N) {
                *reinterpret_cast<uint4*>(vals) =
                    *reinterpret_cast<const uint4*>(&B[(long long)gk * ldb + n0 + nn]);
                *reinterpret_cast<uint4*>(vals + 8) =
                    *reinterpret_cast<const uint4*>(&B[(long long)gk * ldb + n0 + nn + 8]);
            } else {
                #pragma unroll
                for (int i = 0; i < 16; i++) {
                    int gn = n0 + nn + i;
                    vals[i] = (gk < K && gn < N) ? B[(long long)gk * ldb + gn] : (ushort)0;
                }
            }
            #pragma unroll
            for (int i = 0; i < 16; i++) Bs[(nn + i) * LDT + kr] = vals[i];
        }
        __syncthreads();
        #pragma unroll
        for (int kh = 0; kh < KH; kh++) {
            short8v a[MFR], b[NFR];
            int kcol = kh * 32 + (lane >> 4) * 8;
            #pragma unroll
            for (int mi = 0; mi < MFR; mi++)
                a[mi] = *reinterpret_cast<const short8v*>(&As[(wm + mi * 16 + (lane & 15)) * LDT + kcol]);
            #pragma unroll
            for (int ni = 0; ni < NFR; ni++)
                b[ni] = *reinterpret_cast<const short8v*>(&Bs[(wn + ni * 16 + (lane & 15)) * LDT + kcol]);
            #pragma unroll
            for (int mi = 0; mi < MFR; mi++)
                #pragma unroll
                for (int ni = 0; ni < NFR; ni++)
                    acc[mi][ni] = __builtin_amdgcn_mfma_f32_16x16x32_bf16(a[mi], b[ni], acc[mi][ni], 0, 0, 0);
        }
        __syncthreads();
    }
    ushort* C16 = (ushort*)Cv;
    float* C32 = (float*)Cv;
    #pragma unroll
    for (int mi = 0; mi < MFR; mi++) {
        #pragma unroll
        for (int j = 0; j < 4; j++) {
            int gm = m0 + wm + mi * 16 + (lane >> 4) * 4 + j;
            if (gm >= M) continue;
            #pragma unroll
            for (int ni = 0; ni < NFR; ni++) {
                int gn = n0 + wn + ni * 16 + (lane & 15);
                if (gn >= N) continue;
                float v = acc[mi][ni][j] * alpha;
                if (bias) v += bias[gn];
                if (ACT == 1) v = v / (1.f + __expf(-v));
                if (resid) v += resid[(long long)gm * ldr + gn];
                long long ci = bz * sC + (long long)gm * ldc + gn;
                if (OUTBF) C16[ci] = f2b(v); else C32[ci] = v;
            }
        }
    }
}

// ---------------- modulated attention v4 (reverted): LDS-staged, e-chunked (2x12), 2 blocks/CU ----------------
__global__ __launch_bounds__(512, 2) void modattn_kernel(
    ushort* __restrict__ S,
    const float* __restrict__ ap1_w, const float* __restrict__ ap1_b,
    const float* __restrict__ ap2_w, const float* __restrict__ ap2_b) {
    int q = blockIdx.x, tid = threadIdx.x;
    int wid = tid >> 6, lane = tid & 63;
    __shared__ ushort s_lds[6 * KPAD];      // 18912 B
    __shared__ float w1s[144], w2s[144], b1s[24], b2s[6];
    __shared__ float red[8][12];
    __shared__ float fin[12];
    if (tid < 144) { w1s[tid] = ap1_w[tid]; w2s[tid] = ap2_w[tid]; }
    if (tid < 24) b1s[tid] = ap1_b[tid];
    if (tid < 6)  b2s[tid] = ap2_b[tid];
    { // stage S -> LDS, 16B vectors (1182 uint4)
        const uint4* g = reinterpret_cast<const uint4*>(S + (long long)q * QSTR);
        uint4* l = reinterpret_cast<uint4*>(s_lds);
        #pragma unroll
        for (int t = 0; t < 3; t++) {
            int i = tid + t * 512;
            if (i < 1182) l[i] = g[i];
        }
    }
    __syncthreads();
    float a2acc[4][6];
    #pragma unroll
    for (int j = 0; j < 4; j++)
        #pragma unroll
        for (int h = 0; h < 6; h++) a2acc[j][h] = b2s[h];

    #pragma unroll
    for (int c = 0; c < 2; c++) {
        float a1[4][12];
        float r12[12];
        #pragma unroll
        for (int e = 0; e < 12; e++) r12[e] = -3.4e38f;
        #pragma unroll
        for (int j = 0; j < 4; j++) {
            int k = tid + j * 512;
            bool val = k < SEQ;
            int kc = val ? k : 0;
            float sv[6];
            #pragma unroll
            for (int h = 0; h < 6; h++) sv[h] = b2f(s_lds[h * KPAD + kc]);
            #pragma unroll
            for (int e = 0; e < 12; e++) {
                int eg = c * 12 + e;
                float a = b1s[eg];
                #pragma unroll
                for (int h = 0; h < 6; h++) a = fmaf(sv[h], w1s[eg * 6 + h], a);
                a1[j][e] = a;
                if (val) r12[e] = fmaxf(r12[e], a);
            }
        }
        #pragma unroll
        for (int e = 0; e < 12; e++) {
            float v = r12[e];
            #pragma unroll
            for (int off = 32; off >= 1; off >>= 1) v = fmaxf(v, __shfl_xor(v, off));
            r12[e] = v;
        }
        if (lane == 0) {
            #pragma unroll
            for (int e = 0; e < 12; e++) red[wid][e] = r12[e];
        }
        __syncthreads();
        if (tid < 12) {
            float v = red[0][tid];
            #pragma unroll
            for (int w = 1; w < 8; w++) v = fmaxf(v, red[w][tid]);
            fin[tid] = v;
        }
        __syncthreads();
        #pragma unroll
        for (int e = 0; e < 12; e++) r12[e] = 0.f;
        #pragma unroll
        for (int j = 0; j < 4; j++) {
            int k = tid + j * 512;
            bool val = k < SEQ;
            #pragma unroll
            for (int e = 0; e < 12; e++) {
                float p = val ? __expf(a1[j][e] - fin[e]) : 0.f;
                a1[j][e] = p;
                r12[e] += p;
            }
        }
        #pragma unroll
        for (int e = 0; e < 12; e++) {
            float v = r12[e];
            #pragma unroll
            for (int off = 32; off >= 1; off >>= 1) v += __shfl_xor(v, off);
            r12[e] = v;
        }
        if (lane == 0) {
            #pragma unroll
            for (int e = 0; e < 12; e++) red[wid][e] = r12[e];
        }
        __syncthreads();
        if (tid < 12) {
            float v = red[0][tid];
            #pragma unroll
            for (int w = 1; w < 8; w++) v += red[w][tid];
            fin[tid] = 1.f / v;
        }
        __syncthreads();
        #pragma unroll
        for (int j = 0; j < 4; j++) {
            #pragma unroll
            for (int e = 0; e < 12; e++) {
                float p = a1[j][e] * fin[e];
                int eg = c * 12 + e;
                #pragma unroll
                for (int h = 0; h < 6; h++) a2acc[j][h] = fmaf(p, w2s[h * 24 + eg], a2acc[j][h]);
            }
        }
    }
    #pragma unroll
    for (int j = 0; j < 4; j++) {
        int k = tid + j * 512;
        if (k < SEQ) {
            #pragma unroll
            for (int h = 0; h < 6; h++) s_lds[h * KPAD + k] = f2b(a2acc[j][h]);
        } else if (k < KPAD) {
            #pragma unroll
            for (int h = 0; h < 6; h++) s_lds[h * KPAD + k] = 0;
        }
    }
    __syncthreads();
    { // vectorized store LDS -> global
        const uint4* l = reinterpret_cast<const uint4*>(s_lds);
        uint4* g = reinterpret_cast<uint4*>(S + (long long)q * QSTR);
        #pragma unroll
        for (int t = 0; t < 3; t++) {
            int i = tid + t * 512;
            if (i < 1182) g[i] = l[i];
        }
    }
}

// ---------------- single-query attention pooling (per head), vectorized ----------------
__global__ __launch_bounds__(512) void sqa_attn_kernel(const float* __restrict__ kv, const float* __restrict__ qa2,
                                                       float* __restrict__ x1h) {
    int h = blockIdx.x, tid = threadIdx.x;
    int wid = tid >> 6, lane = tid & 63;
    __shared__ float q_s[HD];
    __shared__ float l_s[BROWS];
    __shared__ float red8[8];
    __shared__ float pvred[8][HD];
    __shared__ float gmv;
    if (tid < HD) q_s[tid] = qa2[h * HD + tid];
    __syncthreads();
    float lmax = -1e30f;
    #pragma unroll
    for (int j = 0; j < 4; j++) {
        int s = tid + j * 512;
        if (s < BROWS) {
            const float4* kr = reinterpret_cast<const float4*>(kv + (long long)s * 768 + h * HD);
            float d = 0.f;
            #pragma unroll
            for (int i = 0; i < 16; i++) {
                float4 f = kr[i];
                d = fmaf(f.x, q_s[i * 4 + 0], d); d = fmaf(f.y, q_s[i * 4 + 1], d);
                d = fmaf(f.z, q_s[i * 4 + 2], d); d = fmaf(f.w, q_s[i * 4 + 3], d);
            }
            d *= SCALE;
            l_s[s] = d;
            lmax = fmaxf(lmax, d);
        }
    }
    #pragma unroll
    for (int off = 32; off >= 1; off >>= 1) lmax = fmaxf(lmax, __shfl_xor(lmax, off));
    if (lane == 0) red8[wid] = lmax;
    __syncthreads();
    if (tid == 0) {
        float v = red8[0];
        #pragma unroll
        for (int w = 1; w < 8; w++) v = fmaxf(v, red8[w]);
        gmv = v;
    }
    __syncthreads();
    float gmax = gmv;
    float lsum = 0.f;
    #pragma unroll
    for (int j = 0; j < 4; j++) {
        int s = tid + j * 512;
        if (s < BROWS) { float pp = __expf(l_s[s] - gmax); l_s[s] = pp; lsum += pp; }
    }
    #pragma unroll
    for (int off = 32; off >= 1; off >>= 1) lsum += __shfl_xor(lsum, off);
    if (lane == 0) red8[wid] = lsum;
    __syncthreads();
    if (tid == 0) {
        float v = 0.f;
        #pragma unroll
        for (int w = 0; w < 8; w++) v += red8[w];
        gmv = 1.f / v;
    }
    __syncthreads();
    float inv = gmv;
    int d = tid & 63, g = tid >> 6;
    float acc = 0.f;
    for (int s = g; s < BROWS; s += 8)
        acc = fmaf(l_s[s], kv[(long long)s * 768 + 384 + h * HD + d], acc);
    pvred[g][d] = acc;
    __syncthreads();
    if (tid < HD) {
        float v = 0.f;
        #pragma unroll
        for (int w = 0; w < 8; w++) v += pvred[w][tid];
        x1h[h * HD + tid] = v * inv;
    }
}

// ---------------- sqa mlp: sp1 -> LN -> relu -> sp2 (+ fused qa2 copy to out) ----------------
__global__ __launch_bounds__(384) void sqa_mlp_kernel(const float* __restrict__ x1h,
                                                      const float* __restrict__ sp1_w, const float* __restrict__ sp1_b,
                                                      const float* __restrict__ pn_w, const float* __restrict__ pn_b,
                                                      const float* __restrict__ sp2_w, const float* __restrict__ sp2_b,
                                                      float* __restrict__ z,
                                                      const float* __restrict__ mp, float* __restrict__ dq) {
    __shared__ float y_s[PR];
    __shared__ float x_s[DIM];
    __shared__ float mv[2];
    int tid = threadIdx.x;
    dq[tid] = mp[tid];
    x_s[tid] = x1h[tid];
    __syncthreads();
    if (tid < PR) {
        float a = sp1_b[tid];
        for (int c = 0; c < DIM; c++) a += sp1_w[tid * DIM + c] * x_s[c];
        y_s[tid] = a;
    }
    __syncthreads();
    if (tid == 0) {
        float m = 0.f; for (int i = 0; i < PR; i++) m += y_s[i]; m /= (float)PR;
        float v = 0.f; for (int i = 0; i < PR; i++) { float d = y_s[i] - m; v += d * d; } v /= (float)PR;
        mv[0] = m; mv[1] = rsqrtf(v + EPSV);
    }
    __syncthreads();
    if (tid < PR) {
        float yn = (y_s[tid] - mv[0]) * mv[1] * pn_w[tid] + pn_b[tid];
        y_s[tid] = fmaxf(yn, 0.f);
    }
    __syncthreads();
    float a = sp2_b[tid];
    for (int j = 0; j < PR; j++) a += sp2_w[tid * PR + j] * y_s[j];
    z[tid] = a;
}

// ---------------- scatter + unpatchify + LN1 + residual + LN2 (shuffle reductions) ----------------
__global__ __launch_bounds__(384) void scatter_ln_kernel(
    const float* __restrict__ x, const float* __restrict__ mpout, const ushort* __restrict__ B_bf,
    const float* __restrict__ z, const int* __restrict__ isfg, const int* __restrict__ pos,
    const float* __restrict__ n1w, const float* __restrict__ n1b,
    const float* __restrict__ n2w, const float* __restrict__ n2b,
    float* __restrict__ x_mid, ushort* __restrict__ hnorm_bf) {
    int l = blockIdx.x, c = threadIdx.x;
    int wid = c >> 6, lane = c & 63;
    int hh = l / HS, ww = l % HS;
    int p = (hh >> 1) * 28 + (ww >> 1);
    int t = ((hh & 1) << 1) | (ww & 1);
    float v;
    if (isfg[p]) v = mpout[(long long)(1 + pos[p] * 4 + t) * DIM + c];
    else v = b2f(B_bf[(long long)(pos[p] * 4 + t) * DIM + c]) + z[c];
    __shared__ float r0[8], r1[8], r2[8], r3[8];
    float s1 = v, s2 = v * v;
    #pragma unroll
    for (int off = 32; off >= 1; off >>= 1) { s1 += __shfl_xor(s1, off); s2 += __shfl_xor(s2, off); }
    if (lane == 0) { r0[wid] = s1; r1[wid] = s2; }
    __syncthreads();
    float mean = (r0[0] + r0[1] + r0[2] + r0[3] + r0[4] + r0[5]) / (float)DIM;
    float var = (r1[0] + r1[1] + r1[2] + r1[3] + r1[4] + r1[5]) / (float)DIM - mean * mean;
    float xm = x[(long long)l * DIM + c] + (v - mean) * rsqrtf(var + EPSV) * n1w[c] + n1b[c];
    x_mid[(long long)l * DIM + c] = xm;
    s1 = xm; s2 = xm * xm;
    #pragma unroll
    for (int off = 32; off >= 1; off >>= 1) { s1 += __shfl_xor(s1, off); s2 += __shfl_xor(s2, off); }
    if (lane == 0) { r2[wid] = s1; r3[wid] = s2; }
    __syncthreads();
    float m2 = (r2[0] + r2[1] + r2[2] + r2[3] + r2[4] + r2[5]) / (float)DIM;
    float v2 = (r3[0] + r3[1] + r3[2] + r3[3] + r3[4] + r3[5]) / (float)DIM - m2 * m2;
    hnorm_bf[(long long)l * DIM + c] = f2b((xm - m2) * rsqrtf(v2 + EPSV) * n2w[c] + n2b[c]);
}

extern "C" void kernel_launch(void* const* d_in, const int* in_sizes, int n_in,
                              void* d_out, int out_size, void* d_ws, size_t ws_size,
                              hipStream_t stream) {
    const float* x       = (const float*)d_in[0];
    const float* qa      = (const float*)d_in[1];
    const float* conv_w  = (const float*)d_in[2];
    const float* conv_b  = (const float*)d_in[3];
    const float* n1w     = (const float*)d_in[4];
    const float* n1b     = (const float*)d_in[5];
    const float* n2w     = (const float*)d_in[6];
    const float* n2b     = (const float*)d_in[7];
    const float* qkv_w   = (const float*)d_in[8];
    const float* qkv_b   = (const float*)d_in[9];
    const float* mproj_w = (const float*)d_in[10];
    const float* mproj_b = (const float*)d_in[11];
    const float* ap1_w   = (const float*)d_in[12];
    const float* ap1_b   = (const float*)d_in[13];
    const float* ap2_w   = (const float*)d_in[14];
    const float* ap2_b   = (const float*)d_in[15];
    const float* kv_w    = (const float*)d_in[16];
    const float* kv_b    = (const float*)d_in[17];
    const float* sp1_w   = (const float*)d_in[18];
    const float* sp1_b   = (const float*)d_in[19];
    const float* sp2_w   = (const float*)d_in[20];
    const float* sp2_b   = (const float*)d_in[21];
    const float* pn_w    = (const float*)d_in[22];
    const float* pn_b    = (const float*)d_in[23];
    const float* fc1_w   = (const float*)d_in[24];
    const float* fc1_b   = (const float*)d_in[25];
    const float* fc2_w   = (const float*)d_in[26];
    const float* fc2_b   = (const float*)d_in[27];
    float* out = (float*)d_out;
    float* ws  = (float*)d_ws;

    // ---- workspace layout (float offsets) ----
    const long long X1_OFF    = 0;           // x1 fp32; later qkvb_bf
    const long long BMAT_OFF  = 1204224;     // Bmat_bf (301,056 f as 602,112 u16) — read by kv GEMM AND scatter
    const long long S_OFF     = 1806336;     // S16/A2 bf16 in place; later kv_out/hnorm/hact
    const long long MPOUT_OFF = 16576912;    // Xmsa_bf first, then mpout fp32
    const long long XMID_OFF  = 17179408;    // attn_bf first (dead after mproj), then xmid fp32
    const long long WBF_OFF   = 18383632;
    const long long MEANS_OFF = 19415824;
    const long long X1H_OFF   = 19416608;
    const long long Z_OFF     = 19416992;
    const long long ISFG_OFF  = 19418160;
    const long long POS_OFF   = 19418944;
    const long long FGMAP_OFF = 19419728;
    const long long BGMAP_OFF = 19420120;

    float*  x1_arr  = ws + X1_OFF;
    float*  mpout   = ws + MPOUT_OFF;
    float*  xmid    = ws + XMID_OFF;
    float*  means   = ws + MEANS_OFF;
    float*  x1h     = ws + X1H_OFF;
    float*  zvec    = ws + Z_OFF;
    int*    isfg    = (int*)(ws + ISFG_OFF);
    int*    pos     = (int*)(ws + POS_OFF);
    int*    fgmap   = (int*)(ws + FGMAP_OFF);
    int*    bgmap   = (int*)(ws + BGMAP_OFF);

    ushort* S16     = (ushort*)(ws + S_OFF);
    ushort* qkvb_bf = (ushort*)(ws + X1_OFF);
    ushort* Xmsa_bf = (ushort*)(ws + MPOUT_OFF);
    ushort* Bmat_bf = (ushort*)(ws + BMAT_OFF);          // own slot — NOT aliased with xmid
    ushort* attn_bf = (ushort*)(ws + XMID_OFF);          // dead before scatter writes xmid
    float*  kv_out  = ws + S_OFF;
    ushort* hnorm_bf= (ushort*)(ws + S_OFF + 1204224);
    ushort* hact_bf = (ushort*)(ws + S_OFF + 1806336);

    ushort* wbf      = (ushort*)(ws + WBF_OFF);
    ushort* qkvw_bf  = wbf;
    ushort* mprojw_bf= wbf + 442368;
    ushort* kvw_bf   = wbf + 589824;
    ushort* fc1w_bf  = wbf + 884736;
    ushort* fc2w_bf  = wbf + 1474560;

    { // weight conversion
        CvtSeg s0{qkv_w, qkvw_bf, 442368};
        CvtSeg s1{mproj_w, mprojw_bf, 147456};
        CvtSeg s2{kv_w, kvw_bf, 294912};
        CvtSeg s3{fc1_w, fc1w_bf, 589824};
        CvtSeg s4{fc2_w, fc2w_bf, 589824};
        dim3 g(288, 5, 1);
        cvt_kernel<<<g, 256, 0, stream>>>(s0, s1, s2, s3, s4);
    }

    hipMemsetAsync(means, 0, NPATCH * sizeof(float), stream);
    conv_kernel<<<LPIX, 384, 0, stream>>>(x, conv_w, conv_b, x1_arr, means);
    partition_kernel<<<1, 1024, 0, stream>>>(means, isfg, pos, fgmap, bgmap);
    gather_kernel<<<SEQ + BROWS, 384, 0, stream>>>(x1_arr, qa, fgmap, bgmap, Xmsa_bf, Bmat_bf);

    { // qkv: (1569x384) @ (1152x384)^T -> bf16
        dim3 g(18, 25, 1);
        mgemm<64,64,64,1,0,1><<<g, 256, 0, stream>>>(Xmsa_bf, DIM, 0, qkvw_bf, DIM, 0, qkv_b,
                                                     nullptr, 0, qkvb_bf, 1152, 0, SEQ, 1152, DIM, 1.f);
    }
    { // S[q][h][k] = SCALE * q@k^T -> bf16, batched heads (K=64: single K-step)
        dim3 g(13, 13, 6);
        mgemm<128,128,64,1,0,1><<<g, 256, 0, stream>>>(qkvb_bf, 1152, 64, qkvb_bf + 384, 1152, 64, nullptr,
                                                       nullptr, 0, S16, QSTR, (long long)KPAD, SEQ, SEQ, HD, SCALE);
    }
    modattn_kernel<<<SEQ, 512, 0, stream>>>(S16, ap1_w, ap1_b, ap2_w, ap2_b);
    { // PV: attn_bf[q][h*64+d] = A2[h] @ V[h]
        dim3 g(1, 25, 6);
        mgemm<64,64,64,0,0,1><<<g, 256, 0, stream>>>(S16, QSTR, (long long)KPAD, qkvb_bf + 768, 1152, 64, nullptr,
                                                     nullptr, 0, attn_bf, DIM, 64, SEQ, HD, SEQ, 1.f);
    }
    { // mproj -> fp32 mpout
        dim3 g(6, 25, 1);
        mgemm<64,64,64,1,0,0><<<g, 256, 0, stream>>>(attn_bf, DIM, 0, mprojw_bf, DIM, 0, mproj_b,
                                                     nullptr, 0, mpout, DIM, 0, SEQ, DIM, DIM, 1.f);
    }
    { // kv -> fp32
        dim3 g(12, 25, 1);
        mgemm<64,64,64,1,0,0><<<g, 256, 0, stream>>>(Bmat_bf, DIM, 0, kvw_bf, DIM, 0, kv_b,
                                                     nullptr, 0, kv_out, 768, 0, BROWS, 768, DIM, 1.f);
    }
    sqa_attn_kernel<<<HEADS, 512, 0, stream>>>(kv_out, mpout /* row 0 = qa2 */, x1h);
    sqa_mlp_kernel<<<1, 384, 0, stream>>>(x1h, sp1_w, sp1_b, pn_w, pn_b, sp2_w, sp2_b, zvec,
                                          mpout, out + (long long)LPIX * DIM);
    scatter_ln_kernel<<<LPIX, 384, 0, stream>>>(x, mpout, Bmat_bf, zvec, isfg, pos,
                                                n1w, n1b, n2w, n2b, xmid, hnorm_bf);
    { // fc1 + silu -> bf16
        dim3 g(12, 25, 1);
        mgemm<128,128,64,1,1,1><<<g, 256, 0, stream>>>(hnorm_bf, DIM, 0, fc1w_bf, DIM, 0, fc1_b,
                                                       nullptr, 0, hact_bf, HID, 0, LPIX, HID, DIM, 1.f);
    }
    { // fc2 + residual -> out fp32
        dim3 g(6, 50, 1);
        mgemm<64,64,64,1,0,0><<<g, 256, 0, stream>>>(hact_bf, HID, 0, fc2w_bf, HID, 0, fc2_b,
                                                     xmid, DIM, out, DIM, 0, LPIX, DIM, HID, 1.f);
    }
}

// Round 11
// 507.753 us; speedup vs baseline: 2.2839x; 1.0966x over previous
//
#include <hip/hip_runtime.h>
#include <hip/hip_bf16.h>

#define DIM 384
#define HEADS 6
#define HD 64
#define LPIX 3136
#define HS 56
#define NPATCH 784
#define NF 392
#define SEQ 1569          // 1 + 392*4
#define BROWS 1568
#define HEXP 24
#define PR 96
#define HID 1536
#define SCALE 0.125f
#define EPSV 1e-5f
#define KPAD 1576         // SEQ padded to multiple of 8
#define QSTR 9456         // 6*KPAD, per-q row stride of S/A2 (bf16)

typedef short short8v __attribute__((ext_vector_type(8)));
typedef float f32x4 __attribute__((ext_vector_type(4)));
typedef unsigned short ushort;

__device__ __forceinline__ ushort f2b(float f) {
    __hip_bfloat16 h = __float2bfloat16(f);
    return reinterpret_cast<ushort&>(h);
}
__device__ __forceinline__ float b2f(ushort u) {
    unsigned int ui = ((unsigned int)u) << 16;
    return __uint_as_float(ui);
}

// ---------------- weight fp32 -> bf16 conversion (5 segments in one kernel) ----------------
struct CvtSeg { const float* s; ushort* d; int n; };
__global__ __launch_bounds__(256) void cvt_kernel(CvtSeg a, CvtSeg b, CvtSeg c, CvtSeg d, CvtSeg e) {
    CvtSeg seg;
    switch (blockIdx.y) { case 0: seg = a; break; case 1: seg = b; break; case 2: seg = c; break;
                          case 3: seg = d; break; default: seg = e; break; }
    int idx = (blockIdx.x * 256 + threadIdx.x) * 8;
    if (idx >= seg.n) return;
    float4 f0 = *reinterpret_cast<const float4*>(seg.s + idx);
    float4 f1 = *reinterpret_cast<const float4*>(seg.s + idx + 4);
    ushort u[8] = { f2b(f0.x), f2b(f0.y), f2b(f0.z), f2b(f0.w),
                    f2b(f1.x), f2b(f1.y), f2b(f1.z), f2b(f1.w) };
    *reinterpret_cast<uint4*>(seg.d + idx) = *reinterpret_cast<uint4*>(u);
}

// ---------------- attn fp32 -> bf16 convert (after K-split atomic PV) ----------------
__global__ __launch_bounds__(256) void cvtattn_kernel(const float* __restrict__ s, ushort* __restrict__ d) {
    int idx = (blockIdx.x * 256 + threadIdx.x) * 8;
    if (idx >= SEQ * DIM) return;
    float4 f0 = *reinterpret_cast<const float4*>(s + idx);
    float4 f1 = *reinterpret_cast<const float4*>(s + idx + 4);
    ushort u[8] = { f2b(f0.x), f2b(f0.y), f2b(f0.z), f2b(f0.w),
                    f2b(f1.x), f2b(f1.y), f2b(f1.z), f2b(f1.w) };
    *reinterpret_cast<uint4*>(d + idx) = *reinterpret_cast<uint4*>(u);
}

// ---------------- conv (depthwise 3x3 + bias + residual) + fused patch-sum (means) ----------------
__global__ __launch_bounds__(384) void conv_kernel(const float* __restrict__ x,
                                                   const float* __restrict__ cw,
                                                   const float* __restrict__ cb,
                                                   float* __restrict__ x1,
                                                   float* __restrict__ means) {
    int l = blockIdx.x, c = threadIdx.x;
    int wid = c >> 6, lane = c & 63;
    int hh = l / HS, ww = l % HS;
    float acc = x[(long)l * DIM + c] + cb[c];
    #pragma unroll
    for (int kh = 0; kh < 3; kh++) {
        int h2 = hh + kh - 1;
        if (h2 < 0 || h2 >= HS) continue;
        #pragma unroll
        for (int kw = 0; kw < 3; kw++) {
            int w2 = ww + kw - 1;
            if (w2 < 0 || w2 >= HS) continue;
            acc += x[((long)h2 * HS + w2) * DIM + c] * cw[c * 9 + kh * 3 + kw];
        }
    }
    int p = (hh >> 1) * 28 + (ww >> 1);
    int t = ((hh & 1) << 1) | (ww & 1);
    x1[(long)(p * 4 + t) * DIM + c] = acc;
    float s = acc;
    #pragma unroll
    for (int off = 32; off >= 1; off >>= 1) s += __shfl_xor(s, off);
    __shared__ float wred[6];
    if (lane == 0) wred[wid] = s;
    __syncthreads();
    if (c == 0) atomicAdd(&means[p], wred[0] + wred[1] + wred[2] + wred[3] + wred[4] + wred[5]);
}

// ---------------- partition: rank flags + compaction in one block ----------------
__global__ __launch_bounds__(1024) void partition_kernel(const float* __restrict__ means, int* __restrict__ isfg,
                                                         int* __restrict__ pos, int* __restrict__ fgmap,
                                                         int* __restrict__ bgmap) {
    __shared__ float m_s[NPATCH];
    __shared__ unsigned char flag_s[NPATCH];
    __shared__ int scan_s[256];
    int tid = threadIdx.x;
    if (tid < NPATCH) m_s[tid] = means[tid];
    __syncthreads();
    if (tid < NPATCH) {
        float m = m_s[tid];
        int rank = 0;
        for (int q2 = 0; q2 < NPATCH; q2++) {
            float mq = m_s[q2];
            rank += (mq > m) || (mq == m && q2 < tid);
        }
        flag_s[tid] = (rank < NF) ? 1 : 0;
    }
    __syncthreads();
    if (tid < 256) {
        int base = tid * 4, cnt = 0;
        #pragma unroll
        for (int i = 0; i < 4; i++) { int p = base + i; if (p < NPATCH) cnt += flag_s[p]; }
        scan_s[tid] = cnt;
    }
    __syncthreads();
    for (int off = 1; off < 256; off <<= 1) {
        int add = 0;
        if (tid < 256 && tid >= off) add = scan_s[tid - off];
        __syncthreads();
        if (tid < 256) scan_s[tid] += add;
        __syncthreads();
    }
    if (tid < 256) {
        int base = tid * 4, cnt = 0;
        #pragma unroll
        for (int i = 0; i < 4; i++) { int p = base + i; if (p < NPATCH) cnt += flag_s[p]; }
        int run = scan_s[tid] - cnt;
        for (int i = 0; i < 4; i++) {
            int p = base + i;
            if (p >= NPATCH) break;
            int f = flag_s[p];
            if (f) { isfg[p] = 1; pos[p] = run; fgmap[run] = p; run++; }
            else   { isfg[p] = 0; pos[p] = p - run; bgmap[p - run] = p; }
        }
    }
}

// ---------------- gather foreground (with qa row 0) and background ----------------
__global__ __launch_bounds__(384) void gather_kernel(const float* __restrict__ x1, const float* __restrict__ qa,
                                                     const int* __restrict__ fgmap, const int* __restrict__ bgmap,
                                                     ushort* __restrict__ Xmsa_bf, ushort* __restrict__ B_bf) {
    int c = threadIdx.x;
    int bid = blockIdx.x;
    if (bid == 0) { Xmsa_bf[c] = f2b(qa[c]); return; }
    if (bid <= BROWS) {
        int r = bid - 1;
        int src = fgmap[r >> 2] * 4 + (r & 3);
        Xmsa_bf[(long)bid * DIM + c] = f2b(x1[(long)src * DIM + c]);
    } else {
        int r = bid - SEQ;
        int src = bgmap[r >> 2] * 4 + (r & 3);
        B_bf[(long)r * DIM + c] = f2b(x1[(long)src * DIM + c]);
    }
}

// ---------------- bf16 MFMA GEMM tile body (shared by all GEMM kernels) ----------------
struct GArgs {
    const ushort* A; int lda;
    const ushort* B; int ldb;
    const float* bias; const float* resid; int ldr;
    void* C; int ldc;
    int M, N, K; float alpha;
};

// OPB=1: B is [N][K] bf16 (A@B^T). OPB=0: B is [K][N] bf16 (requires BN=64, BK=64).
// ATOMIC=1: fp32 atomicAdd into C (no bias/resid/act).
template<int BM, int BN, int BK, int OPB, int ACT, int OUTBF, int ATOMIC>
__device__ __forceinline__ void gemm_tile(const GArgs g, int bx, int by, ushort* As, ushort* Bs) {
    constexpr int LDT = BK + 8;
    constexpr int WR = (BM == 128 && BN == 128) ? 2 : ((BM == 128) ? 4 : 2);
    constexpr int WC = 4 / WR;
    constexpr int MFR = BM / WR / 16;
    constexpr int NFR = BN / WC / 16;
    constexpr int KH = BK / 32;
    int tid = threadIdx.x;
    int wid = tid >> 6, lane = tid & 63;
    int m0 = by * BM, n0 = bx * BN;
    int wm = (wid / WC) * (BM / WR);
    int wn = (wid % WC) * (BN / WC);
    f32x4 acc[MFR][NFR];
    #pragma unroll
    for (int mi = 0; mi < MFR; mi++)
        #pragma unroll
        for (int ni = 0; ni < NFR; ni++) acc[mi][ni] = (f32x4){0.f, 0.f, 0.f, 0.f};

    for (int k0 = 0; k0 < g.K; k0 += BK) {
        { // ---- stage A: BM x BK ----
            constexpr int CPR = BK / 8;
            constexpr int CHA = BM * CPR / 256;
            #pragma unroll
            for (int t = 0; t < CHA; t++) {
                int chunk = tid + t * 256;
                int row = chunk / CPR, part = chunk % CPR;
                int gm = m0 + row, gk = k0 + part * 8;
                ushort* dst = &As[row * LDT + part * 8];
                if (gm < g.M && gk + 8 <= g.K) {
                    *reinterpret_cast<uint4*>(dst) =
                        *reinterpret_cast<const uint4*>(&g.A[(long long)gm * g.lda + gk]);
                } else {
                    #pragma unroll
                    for (int i = 0; i < 8; i++) {
                        int k = gk + i;
                        dst[i] = (gm < g.M && k < g.K) ? g.A[(long long)gm * g.lda + k] : (ushort)0;
                    }
                }
            }
        }
        if (OPB == 1) { // ---- stage B: BN x BK from [N][K] ----
            constexpr int CPR = BK / 8;
            constexpr int CHB = BN * CPR / 256;
            #pragma unroll
            for (int t = 0; t < CHB; t++) {
                int chunk = tid + t * 256;
                int row = chunk / CPR, part = chunk % CPR;
                int gn = n0 + row, gk = k0 + part * 8;
                ushort* dst = &Bs[row * LDT + part * 8];
                if (gn < g.N && gk + 8 <= g.K) {
                    *reinterpret_cast<uint4*>(dst) =
                        *reinterpret_cast<const uint4*>(&g.B[(long long)gn * g.ldb + gk]);
                } else {
                    #pragma unroll
                    for (int i = 0; i < 8; i++) {
                        int k = gk + i;
                        dst[i] = (gn < g.N && k < g.K) ? g.B[(long long)gn * g.ldb + k] : (ushort)0;
                    }
                }
            }
        } else { // ---- stage B: BK x BN from [K][N], transpose (BK=64, BN=64) ----
            int kr = tid >> 2, nn = (tid & 3) * 16;
            int gk = k0 + kr;
            ushort vals[16];
            if (gk < g.K && n0 + nn + 16 <= g.N) {
                *reinterpret_cast<uint4*>(vals) =
                    *reinterpret_cast<const uint4*>(&g.B[(long long)gk * g.ldb + n0 + nn]);
                *reinterpret_cast<uint4*>(vals + 8) =
                    *reinterpret_cast<const uint4*>(&g.B[(long long)gk * g.ldb + n0 + nn + 8]);
            } else {
                #pragma unroll
                for (int i = 0; i < 16; i++) {
                    int gn = n0 + nn + i;
                    vals[i] = (gk < g.K && gn < g.N) ? g.B[(long long)gk * g.ldb + gn] : (ushort)0;
                }
            }
            #pragma unroll
            for (int i = 0; i < 16; i++) Bs[(nn + i) * LDT + kr] = vals[i];
        }
        __syncthreads();
        #pragma unroll
        for (int kh = 0; kh < KH; kh++) {
            short8v a[MFR], b[NFR];
            int kcol = kh * 32 + (lane >> 4) * 8;
            #pragma unroll
            for (int mi = 0; mi < MFR; mi++)
                a[mi] = *reinterpret_cast<const short8v*>(&As[(wm + mi * 16 + (lane & 15)) * LDT + kcol]);
            #pragma unroll
            for (int ni = 0; ni < NFR; ni++)
                b[ni] = *reinterpret_cast<const short8v*>(&Bs[(wn + ni * 16 + (lane & 15)) * LDT + kcol]);
            #pragma unroll
            for (int mi = 0; mi < MFR; mi++)
                #pragma unroll
                for (int ni = 0; ni < NFR; ni++)
                    acc[mi][ni] = __builtin_amdgcn_mfma_f32_16x16x32_bf16(a[mi], b[ni], acc[mi][ni], 0, 0, 0);
        }
        __syncthreads();
    }
    ushort* C16 = (ushort*)g.C;
    float* C32 = (float*)g.C;
    #pragma unroll
    for (int mi = 0; mi < MFR; mi++) {
        #pragma unroll
        for (int j = 0; j < 4; j++) {
            int gm = m0 + wm + mi * 16 + (lane >> 4) * 4 + j;
            if (gm >= g.M) continue;
            #pragma unroll
            for (int ni = 0; ni < NFR; ni++) {
                int gn = n0 + wn + ni * 16 + (lane & 15);
                if (gn >= g.N) continue;
                float v = acc[mi][ni][j] * g.alpha;
                long long ci = (long long)gm * g.ldc + gn;
                if (ATOMIC) {
                    atomicAdd(&C32[ci], v);
                } else {
                    if (g.bias) v += g.bias[gn];
                    if (ACT == 1) v = v / (1.f + __expf(-v));
                    if (g.resid) v += g.resid[(long long)gm * g.ldr + gn];
                    if (OUTBF) C16[ci] = f2b(v); else C32[ci] = v;
                }
            }
        }
    }
}

// batched GEMM wrapper (z = batch)
template<int BM, int BN, int BK, int OPB, int ACT, int OUTBF>
__global__ __launch_bounds__(256) void mgemm(
    const ushort* A, int lda, long long sA,
    const ushort* B, int ldb, long long sB,
    const float* bias, const float* resid, int ldr,
    void* Cv, int ldc, long long sC,
    int M, int N, int K, float alpha) {
    __shared__ ushort As[BM * (BK + 8)];
    __shared__ ushort Bs[BN * (BK + 8)];
    GArgs g;
    g.A = A + (long long)blockIdx.z * sA; g.lda = lda;
    g.B = B + (long long)blockIdx.z * sB; g.ldb = ldb;
    g.bias = bias; g.resid = resid; g.ldr = ldr;
    g.C = OUTBF ? (void*)((ushort*)Cv + (long long)blockIdx.z * sC)
                : (void*)((float*)Cv + (long long)blockIdx.z * sC);
    g.ldc = ldc; g.M = M; g.N = N; g.K = K; g.alpha = alpha;
    gemm_tile<BM, BN, BK, OPB, ACT, OUTBF, 0>(g, blockIdx.x, blockIdx.y, As, Bs);
}

// two independent GEMMs (same 64x64x64 OPB=1 fp32-out config) in one launch
__global__ __launch_bounds__(256) void mgemm_dual(GArgs a, GArgs b, int xsplit) {
    __shared__ ushort As[64 * 72];
    __shared__ ushort Bs[64 * 72];
    if ((int)blockIdx.x < xsplit) gemm_tile<64, 64, 64, 1, 0, 0, 0>(a, blockIdx.x, blockIdx.y, As, Bs);
    else                          gemm_tile<64, 64, 64, 1, 0, 0, 0>(b, blockIdx.x - xsplit, blockIdx.y, As, Bs);
}

// PV with K-split: z = h*4 + ks, fp32 atomic accumulation into attn_f32
__global__ __launch_bounds__(256) void pv_kernel(const ushort* __restrict__ S16, const ushort* __restrict__ V,
                                                 float* __restrict__ attn_f32) {
    __shared__ ushort As[64 * 72];
    __shared__ ushort Bs[64 * 72];
    int z = blockIdx.z;
    int h = z >> 2, ks = z & 3;
    int kbeg = ks * 400;
    int kend = (kbeg + 400 < SEQ) ? kbeg + 400 : SEQ;
    GArgs g;
    g.A = S16 + h * KPAD + kbeg; g.lda = QSTR;
    g.B = V + h * HD + (long long)kbeg * 1152; g.ldb = 1152;
    g.bias = nullptr; g.resid = nullptr; g.ldr = 0;
    g.C = attn_f32 + h * HD; g.ldc = DIM;
    g.M = SEQ; g.N = HD; g.K = kend - kbeg; g.alpha = 1.f;
    gemm_tile<64, 64, 64, 0, 0, 0, 1>(g, 0, blockIdx.y, As, Bs);
}

// ---------------- modulated attention v4: LDS-staged, e-chunked (2x12), 2 blocks/CU ----------------
__global__ __launch_bounds__(512, 2) void modattn_kernel(
    ushort* __restrict__ S,
    const float* __restrict__ ap1_w, const float* __restrict__ ap1_b,
    const float* __restrict__ ap2_w, const float* __restrict__ ap2_b) {
    int q = blockIdx.x, tid = threadIdx.x;
    int wid = tid >> 6, lane = tid & 63;
    __shared__ ushort s_lds[6 * KPAD];      // 18912 B
    __shared__ float w1s[144], w2s[144], b1s[24], b2s[6];
    __shared__ float red[8][12];
    __shared__ float fin[12];
    if (tid < 144) { w1s[tid] = ap1_w[tid]; w2s[tid] = ap2_w[tid]; }
    if (tid < 24) b1s[tid] = ap1_b[tid];
    if (tid < 6)  b2s[tid] = ap2_b[tid];
    { // stage S -> LDS, 16B vectors (1182 uint4)
        const uint4* g = reinterpret_cast<const uint4*>(S + (long long)q * QSTR);
        uint4* l = reinterpret_cast<uint4*>(s_lds);
        #pragma unroll
        for (int t = 0; t < 3; t++) {
            int i = tid + t * 512;
            if (i < 1182) l[i] = g[i];
        }
    }
    __syncthreads();
    float a2acc[4][6];
    #pragma unroll
    for (int j = 0; j < 4; j++)
        #pragma unroll
        for (int h = 0; h < 6; h++) a2acc[j][h] = b2s[h];

    #pragma unroll
    for (int c = 0; c < 2; c++) {
        float a1[4][12];
        float r12[12];
        #pragma unroll
        for (int e = 0; e < 12; e++) r12[e] = -3.4e38f;
        #pragma unroll
        for (int j = 0; j < 4; j++) {
            int k = tid + j * 512;
            bool val = k < SEQ;
            int kc = val ? k : 0;
            float sv[6];
            #pragma unroll
            for (int h = 0; h < 6; h++) sv[h] = b2f(s_lds[h * KPAD + kc]);
            #pragma unroll
            for (int e = 0; e < 12; e++) {
                int eg = c * 12 + e;
                float a = b1s[eg];
                #pragma unroll
                for (int h = 0; h < 6; h++) a = fmaf(sv[h], w1s[eg * 6 + h], a);
                a1[j][e] = a;
                if (val) r12[e] = fmaxf(r12[e], a);
            }
        }
        #pragma unroll
        for (int e = 0; e < 12; e++) {
            float v = r12[e];
            #pragma unroll
            for (int off = 32; off >= 1; off >>= 1) v = fmaxf(v, __shfl_xor(v, off));
            r12[e] = v;
        }
        if (lane == 0) {
            #pragma unroll
            for (int e = 0; e < 12; e++) red[wid][e] = r12[e];
        }
        __syncthreads();
        if (tid < 12) {
            float v = red[0][tid];
            #pragma unroll
            for (int w = 1; w < 8; w++) v = fmaxf(v, red[w][tid]);
            fin[tid] = v;
        }
        __syncthreads();
        #pragma unroll
        for (int e = 0; e < 12; e++) r12[e] = 0.f;
        #pragma unroll
        for (int j = 0; j < 4; j++) {
            int k = tid + j * 512;
            bool val = k < SEQ;
            #pragma unroll
            for (int e = 0; e < 12; e++) {
                float p = val ? __expf(a1[j][e] - fin[e]) : 0.f;
                a1[j][e] = p;
                r12[e] += p;
            }
        }
        #pragma unroll
        for (int e = 0; e < 12; e++) {
            float v = r12[e];
            #pragma unroll
            for (int off = 32; off >= 1; off >>= 1) v += __shfl_xor(v, off);
            r12[e] = v;
        }
        if (lane == 0) {
            #pragma unroll
            for (int e = 0; e < 12; e++) red[wid][e] = r12[e];
        }
        __syncthreads();
        if (tid < 12) {
            float v = red[0][tid];
            #pragma unroll
            for (int w = 1; w < 8; w++) v += red[w][tid];
            fin[tid] = 1.f / v;
        }
        __syncthreads();
        #pragma unroll
        for (int j = 0; j < 4; j++) {
            #pragma unroll
            for (int e = 0; e < 12; e++) {
                float p = a1[j][e] * fin[e];
                int eg = c * 12 + e;
                #pragma unroll
                for (int h = 0; h < 6; h++) a2acc[j][h] = fmaf(p, w2s[h * 24 + eg], a2acc[j][h]);
            }
        }
    }
    #pragma unroll
    for (int j = 0; j < 4; j++) {
        int k = tid + j * 512;
        if (k < SEQ) {
            #pragma unroll
            for (int h = 0; h < 6; h++) s_lds[h * KPAD + k] = f2b(a2acc[j][h]);
        } else if (k < KPAD) {
            #pragma unroll
            for (int h = 0; h < 6; h++) s_lds[h * KPAD + k] = 0;
        }
    }
    __syncthreads();
    { // vectorized store LDS -> global
        const uint4* l = reinterpret_cast<const uint4*>(s_lds);
        uint4* g = reinterpret_cast<uint4*>(S + (long long)q * QSTR);
        #pragma unroll
        for (int t = 0; t < 3; t++) {
            int i = tid + t * 512;
            if (i < 1182) g[i] = l[i];
        }
    }
}

// ---------------- single-query attention pooling (per head), vectorized ----------------
__global__ __launch_bounds__(512) void sqa_attn_kernel(const float* __restrict__ kv, const float* __restrict__ qa2,
                                                       float* __restrict__ x1h) {
    int h = blockIdx.x, tid = threadIdx.x;
    int wid = tid >> 6, lane = tid & 63;
    __shared__ float q_s[HD];
    __shared__ float l_s[BROWS];
    __shared__ float red8[8];
    __shared__ float pvred[8][HD];
    __shared__ float gmv;
    if (tid < HD) q_s[tid] = qa2[h * HD + tid];
    __syncthreads();
    float lmax = -1e30f;
    #pragma unroll
    for (int j = 0; j < 4; j++) {
        int s = tid + j * 512;
        if (s < BROWS) {
            const float4* kr = reinterpret_cast<const float4*>(kv + (long long)s * 768 + h * HD);
            float d = 0.f;
            #pragma unroll
            for (int i = 0; i < 16; i++) {
                float4 f = kr[i];
                d = fmaf(f.x, q_s[i * 4 + 0], d); d = fmaf(f.y, q_s[i * 4 + 1], d);
                d = fmaf(f.z, q_s[i * 4 + 2], d); d = fmaf(f.w, q_s[i * 4 + 3], d);
            }
            d *= SCALE;
            l_s[s] = d;
            lmax = fmaxf(lmax, d);
        }
    }
    #pragma unroll
    for (int off = 32; off >= 1; off >>= 1) lmax = fmaxf(lmax, __shfl_xor(lmax, off));
    if (lane == 0) red8[wid] = lmax;
    __syncthreads();
    if (tid == 0) {
        float v = red8[0];
        #pragma unroll
        for (int w = 1; w < 8; w++) v = fmaxf(v, red8[w]);
        gmv = v;
    }
    __syncthreads();
    float gmax = gmv;
    float lsum = 0.f;
    #pragma unroll
    for (int j = 0; j < 4; j++) {
        int s = tid + j * 512;
        if (s < BROWS) { float pp = __expf(l_s[s] - gmax); l_s[s] = pp; lsum += pp; }
    }
    #pragma unroll
    for (int off = 32; off >= 1; off >>= 1) lsum += __shfl_xor(lsum, off);
    if (lane == 0) red8[wid] = lsum;
    __syncthreads();
    if (tid == 0) {
        float v = 0.f;
        #pragma unroll
        for (int w = 0; w < 8; w++) v += red8[w];
        gmv = 1.f / v;
    }
    __syncthreads();
    float inv = gmv;
    int d = tid & 63, g = tid >> 6;
    float acc = 0.f;
    for (int s = g; s < BROWS; s += 8)
        acc = fmaf(l_s[s], kv[(long long)s * 768 + 384 + h * HD + d], acc);
    pvred[g][d] = acc;
    __syncthreads();
    if (tid < HD) {
        float v = 0.f;
        #pragma unroll
        for (int w = 0; w < 8; w++) v += pvred[w][tid];
        x1h[h * HD + tid] = v * inv;
    }
}

// ---------------- sqa mlp: sp1 -> LN -> relu -> sp2 (+ fused qa2 copy to out) ----------------
__global__ __launch_bounds__(384) void sqa_mlp_kernel(const float* __restrict__ x1h,
                                                      const float* __restrict__ sp1_w, const float* __restrict__ sp1_b,
                                                      const float* __restrict__ pn_w, const float* __restrict__ pn_b,
                                                      const float* __restrict__ sp2_w, const float* __restrict__ sp2_b,
                                                      float* __restrict__ z,
                                                      const float* __restrict__ mp, float* __restrict__ dq) {
    __shared__ float y_s[PR];
    __shared__ float x_s[DIM];
    __shared__ float mv[2];
    int tid = threadIdx.x;
    dq[tid] = mp[tid];
    x_s[tid] = x1h[tid];
    __syncthreads();
    if (tid < PR) {
        float a = sp1_b[tid];
        for (int c = 0; c < DIM; c++) a += sp1_w[tid * DIM + c] * x_s[c];
        y_s[tid] = a;
    }
    __syncthreads();
    if (tid == 0) {
        float m = 0.f; for (int i = 0; i < PR; i++) m += y_s[i]; m /= (float)PR;
        float v = 0.f; for (int i = 0; i < PR; i++) { float d = y_s[i] - m; v += d * d; } v /= (float)PR;
        mv[0] = m; mv[1] = rsqrtf(v + EPSV);
    }
    __syncthreads();
    if (tid < PR) {
        float yn = (y_s[tid] - mv[0]) * mv[1] * pn_w[tid] + pn_b[tid];
        y_s[tid] = fmaxf(yn, 0.f);
    }
    __syncthreads();
    float a = sp2_b[tid];
    for (int j = 0; j < PR; j++) a += sp2_w[tid * PR + j] * y_s[j];
    z[tid] = a;
}

// ---------------- scatter + unpatchify + LN1 + residual + LN2 (shuffle reductions) ----------------
__global__ __launch_bounds__(384) void scatter_ln_kernel(
    const float* __restrict__ x, const float* __restrict__ mpout, const ushort* __restrict__ B_bf,
    const float* __restrict__ z, const int* __restrict__ isfg, const int* __restrict__ pos,
    const float* __restrict__ n1w, const float* __restrict__ n1b,
    const float* __restrict__ n2w, const float* __restrict__ n2b,
    float* __restrict__ x_mid, ushort* __restrict__ hnorm_bf) {
    int l = blockIdx.x, c = threadIdx.x;
    int wid = c >> 6, lane = c & 63;
    int hh = l / HS, ww = l % HS;
    int p = (hh >> 1) * 28 + (ww >> 1);
    int t = ((hh & 1) << 1) | (ww & 1);
    float v;
    if (isfg[p]) v = mpout[(long long)(1 + pos[p] * 4 + t) * DIM + c];
    else v = b2f(B_bf[(long long)(pos[p] * 4 + t) * DIM + c]) + z[c];
    __shared__ float r0[8], r1[8], r2[8], r3[8];
    float s1 = v, s2 = v * v;
    #pragma unroll
    for (int off = 32; off >= 1; off >>= 1) { s1 += __shfl_xor(s1, off); s2 += __shfl_xor(s2, off); }
    if (lane == 0) { r0[wid] = s1; r1[wid] = s2; }
    __syncthreads();
    float mean = (r0[0] + r0[1] + r0[2] + r0[3] + r0[4] + r0[5]) / (float)DIM;
    float var = (r1[0] + r1[1] + r1[2] + r1[3] + r1[4] + r1[5]) / (float)DIM - mean * mean;
    float xm = x[(long long)l * DIM + c] + (v - mean) * rsqrtf(var + EPSV) * n1w[c] + n1b[c];
    x_mid[(long long)l * DIM + c] = xm;
    s1 = xm; s2 = xm * xm;
    #pragma unroll
    for (int off = 32; off >= 1; off >>= 1) { s1 += __shfl_xor(s1, off); s2 += __shfl_xor(s2, off); }
    if (lane == 0) { r2[wid] = s1; r3[wid] = s2; }
    __syncthreads();
    float m2 = (r2[0] + r2[1] + r2[2] + r2[3] + r2[4] + r2[5]) / (float)DIM;
    float v2 = (r3[0] + r3[1] + r3[2] + r3[3] + r3[4] + r3[5]) / (float)DIM - m2 * m2;
    hnorm_bf[(long long)l * DIM + c] = f2b((xm - m2) * rsqrtf(v2 + EPSV) * n2w[c] + n2b[c]);
}

extern "C" void kernel_launch(void* const* d_in, const int* in_sizes, int n_in,
                              void* d_out, int out_size, void* d_ws, size_t ws_size,
                              hipStream_t stream) {
    const float* x       = (const float*)d_in[0];
    const float* qa      = (const float*)d_in[1];
    const float* conv_w  = (const float*)d_in[2];
    const float* conv_b  = (const float*)d_in[3];
    const float* n1w     = (const float*)d_in[4];
    const float* n1b     = (const float*)d_in[5];
    const float* n2w     = (const float*)d_in[6];
    const float* n2b     = (const float*)d_in[7];
    const float* qkv_w   = (const float*)d_in[8];
    const float* qkv_b   = (const float*)d_in[9];
    const float* mproj_w = (const float*)d_in[10];
    const float* mproj_b = (const float*)d_in[11];
    const float* ap1_w   = (const float*)d_in[12];
    const float* ap1_b   = (const float*)d_in[13];
    const float* ap2_w   = (const float*)d_in[14];
    const float* ap2_b   = (const float*)d_in[15];
    const float* kv_w    = (const float*)d_in[16];
    const float* kv_b    = (const float*)d_in[17];
    const float* sp1_w   = (const float*)d_in[18];
    const float* sp1_b   = (const float*)d_in[19];
    const float* sp2_w   = (const float*)d_in[20];
    const float* sp2_b   = (const float*)d_in[21];
    const float* pn_w    = (const float*)d_in[22];
    const float* pn_b    = (const float*)d_in[23];
    const float* fc1_w   = (const float*)d_in[24];
    const float* fc1_b   = (const float*)d_in[25];
    const float* fc2_w   = (const float*)d_in[26];
    const float* fc2_b   = (const float*)d_in[27];
    float* out = (float*)d_out;
    float* ws  = (float*)d_ws;

    // ---- workspace layout (float offsets) ----
    const long long X1_OFF    = 0;           // x1 fp32; later qkvb_bf
    const long long BMAT_OFF  = 1204224;     // Bmat_bf
    const long long S_OFF     = 1806336;     // S16/A2 bf16 in place; later kv_out/hnorm/hact
    const long long MPOUT_OFF = 16576912;    // Xmsa_bf first, then mpout fp32
    const long long XMID_OFF  = 17179408;    // attn_f32 [0,602496) + attn_bf u16 at +602496; later xmid fp32
    const long long WBF_OFF   = 18383632;
    const long long MEANS_OFF = 19415824;
    const long long X1H_OFF   = 19416608;
    const long long Z_OFF     = 19416992;
    const long long ISFG_OFF  = 19418160;
    const long long POS_OFF   = 19418944;
    const long long FGMAP_OFF = 19419728;
    const long long BGMAP_OFF = 19420120;

    float*  x1_arr  = ws + X1_OFF;
    float*  mpout   = ws + MPOUT_OFF;
    float*  xmid    = ws + XMID_OFF;
    float*  means   = ws + MEANS_OFF;
    float*  x1h     = ws + X1H_OFF;
    float*  zvec    = ws + Z_OFF;
    int*    isfg    = (int*)(ws + ISFG_OFF);
    int*    pos     = (int*)(ws + POS_OFF);
    int*    fgmap   = (int*)(ws + FGMAP_OFF);
    int*    bgmap   = (int*)(ws + BGMAP_OFF);

    ushort* S16     = (ushort*)(ws + S_OFF);
    ushort* qkvb_bf = (ushort*)(ws + X1_OFF);
    ushort* Xmsa_bf = (ushort*)(ws + MPOUT_OFF);
    ushort* Bmat_bf = (ushort*)(ws + BMAT_OFF);
    float*  attn_f32= ws + XMID_OFF;                       // dead before scatter writes xmid
    ushort* attn_bf = (ushort*)(ws + XMID_OFF + 602496);   // dead before scatter writes xmid
    float*  kv_out  = ws + S_OFF;
    ushort* hnorm_bf= (ushort*)(ws + S_OFF + 1204224);
    ushort* hact_bf = (ushort*)(ws + S_OFF + 1806336);

    ushort* wbf      = (ushort*)(ws + WBF_OFF);
    ushort* qkvw_bf  = wbf;
    ushort* mprojw_bf= wbf + 442368;
    ushort* kvw_bf   = wbf + 589824;
    ushort* fc1w_bf  = wbf + 884736;
    ushort* fc2w_bf  = wbf + 1474560;

    { // weight conversion
        CvtSeg s0{qkv_w, qkvw_bf, 442368};
        CvtSeg s1{mproj_w, mprojw_bf, 147456};
        CvtSeg s2{kv_w, kvw_bf, 294912};
        CvtSeg s3{fc1_w, fc1w_bf, 589824};
        CvtSeg s4{fc2_w, fc2w_bf, 589824};
        dim3 g(288, 5, 1);
        cvt_kernel<<<g, 256, 0, stream>>>(s0, s1, s2, s3, s4);
    }

    hipMemsetAsync(means, 0, NPATCH * sizeof(float), stream);
    hipMemsetAsync(attn_f32, 0, (size_t)SEQ * DIM * sizeof(float), stream);
    conv_kernel<<<LPIX, 384, 0, stream>>>(x, conv_w, conv_b, x1_arr, means);
    partition_kernel<<<1, 1024, 0, stream>>>(means, isfg, pos, fgmap, bgmap);
    gather_kernel<<<SEQ + BROWS, 384, 0, stream>>>(x1_arr, qa, fgmap, bgmap, Xmsa_bf, Bmat_bf);

    { // qkv: (1569x384) @ (1152x384)^T -> bf16
        dim3 g(18, 25, 1);
        mgemm<64,64,64,1,0,1><<<g, 256, 0, stream>>>(Xmsa_bf, DIM, 0, qkvw_bf, DIM, 0, qkv_b,
                                                     nullptr, 0, qkvb_bf, 1152, 0, SEQ, 1152, DIM, 1.f);
    }
    { // S[q][h][k] = SCALE * q@k^T -> bf16, batched heads (K=64: single K-step)
        dim3 g(13, 13, 6);
        mgemm<128,128,64,1,0,1><<<g, 256, 0, stream>>>(qkvb_bf, 1152, 64, qkvb_bf + 384, 1152, 64, nullptr,
                                                       nullptr, 0, S16, QSTR, (long long)KPAD, SEQ, SEQ, HD, SCALE);
    }
    modattn_kernel<<<SEQ, 512, 0, stream>>>(S16, ap1_w, ap1_b, ap2_w, ap2_b);
    { // PV: K-split x4 per head, atomic fp32 accumulation (600 blocks)
        dim3 g(1, 25, 24);
        pv_kernel<<<g, 256, 0, stream>>>(S16, qkvb_bf + 768, attn_f32);
    }
    cvtattn_kernel<<<295, 256, 0, stream>>>(attn_f32, attn_bf);
    { // mproj (x<6) + kv (x>=6) merged: 18x25 blocks
        GArgs gm_;
        gm_.A = attn_bf; gm_.lda = DIM; gm_.B = mprojw_bf; gm_.ldb = DIM;
        gm_.bias = mproj_b; gm_.resid = nullptr; gm_.ldr = 0;
        gm_.C = mpout; gm_.ldc = DIM; gm_.M = SEQ; gm_.N = DIM; gm_.K = DIM; gm_.alpha = 1.f;
        GArgs gk_;
        gk_.A = Bmat_bf; gk_.lda = DIM; gk_.B = kvw_bf; gk_.ldb = DIM;
        gk_.bias = kv_b; gk_.resid = nullptr; gk_.ldr = 0;
        gk_.C = kv_out; gk_.ldc = 768; gk_.M = BROWS; gk_.N = 768; gk_.K = DIM; gk_.alpha = 1.f;
        dim3 g(18, 25, 1);
        mgemm_dual<<<g, 256, 0, stream>>>(gm_, gk_, 6);
    }
    sqa_attn_kernel<<<HEADS, 512, 0, stream>>>(kv_out, mpout /* row 0 = qa2 */, x1h);
    sqa_mlp_kernel<<<1, 384, 0, stream>>>(x1h, sp1_w, sp1_b, pn_w, pn_b, sp2_w, sp2_b, zvec,
                                          mpout, out + (long long)LPIX * DIM);
    scatter_ln_kernel<<<LPIX, 384, 0, stream>>>(x, mpout, Bmat_bf, zvec, isfg, pos,
                                                n1w, n1b, n2w, n2b, xmid, hnorm_bf);
    { // fc1 + silu -> bf16 (64x64 tiles: 1176 blocks)
        dim3 g(24, 49, 1);
        mgemm<64,64,64,1,1,1><<<g, 256, 0, stream>>>(hnorm_bf, DIM, 0, fc1w_bf, DIM, 0, fc1_b,
                                                     nullptr, 0, hact_bf, HID, 0, LPIX, HID, DIM, 1.f);
    }
    { // fc2 + residual -> out fp32
        dim3 g(6, 49, 1);
        mgemm<64,64,64,1,0,0><<<g, 256, 0, stream>>>(hact_bf, HID, 0, fc2w_bf, HID, 0, fc2_b,
                                                     xmid, DIM, out, DIM, 0, LPIX, DIM, HID, 1.f);
    }
}